// Round 2
// baseline (517.781 us; speedup 1.0000x reference)
//
#include <hip/hip_runtime.h>
#include <math.h>

typedef unsigned short u16;
typedef unsigned int   u32;
using short8  = __attribute__((ext_vector_type(8))) short;
using float4v = __attribute__((ext_vector_type(4))) float;

__device__ __forceinline__ float b2f(u16 u){ return __uint_as_float(((u32)u)<<16); }
__device__ __forceinline__ u16 f2b(float f){
  u32 x = __float_as_uint(f);
  x += 0x7FFFu + ((x>>16)&1u);   // RNE; inputs are tame (no NaN)
  return (u16)(x>>16);
}

// ---------------- weight transpose + fp32->bf16: [R][C] fp32 -> [C][R] bf16 ----------------
__global__ void transpose_kernel(const float* __restrict__ src, u16* __restrict__ dst, int R, int Cc){
  int idx = blockIdx.x*256 + threadIdx.x;
  if (idx < R*Cc){
    int r = idx / Cc, c = idx - r*Cc;
    dst[c*R + r] = f2b(src[idx]);
  }
}

// ---------------- LayerNorm (fp32 in, bf16 out); PART=true: roll(-2) + window partition ----------------
template<bool PART>
__global__ __launch_bounds__(256) void ln_kernel(const float* __restrict__ x,
    const float* __restrict__ g, const float* __restrict__ bvec,
    u16* __restrict__ out)
{
  int wave = threadIdx.x >> 6, lane = threadIdx.x & 63;
  int token = blockIdx.x*4 + wave;          // 0..65535
  int src, dst;
  if (PART){
    int b = token >> 15, r = token & 32767; // token enumerates SHIFTED coords
    int hs = r >> 10, ws = (r >> 5) & 31, ds = r & 31;
    int h = (hs+2)&31, w = (ws+2)&31, d = (ds+2)&31;   // sx[hs] = xn[(hs+2)%32]
    src = ((b*32 + h)*32 + w)*32 + d;
    int win = ((b*8 + (hs>>2))*8 + (ws>>2))*8 + (ds>>2);
    int n   = ((hs&3)*4 + (ws&3))*4 + (ds&3);
    dst = win*64 + n;
  } else { src = token; dst = token; }
  float v[3];
  #pragma unroll
  for (int t=0;t<3;t++) v[t] = x[(size_t)src*192 + lane + t*64];
  float s  = v[0]+v[1]+v[2];
  float s2 = v[0]*v[0]+v[1]*v[1]+v[2]*v[2];
  #pragma unroll
  for (int o=32;o>=1;o>>=1){ s += __shfl_xor(s,o); s2 += __shfl_xor(s2,o); }
  float mean = s*(1.0f/192.0f);
  float var  = s2*(1.0f/192.0f) - mean*mean;
  float rstd = rsqrtf(var + 1e-5f);
  #pragma unroll
  for (int t=0;t<3;t++){
    int c = lane + t*64;
    out[(size_t)dst*192 + c] = f2b((v[t]-mean)*rstd*g[c] + bvec[c]);
  }
}

// ---------------- MFMA GEMM: C[M][N] = A[M][K] @ BT[N][K]^T + bias ----------------
// 64x64 tile, 4 waves, mfma_f32_16x16x32_bf16.
// A frag: m=lane&15, k=quad*8+j ; B frag: n=lane&15, k=quad*8+j ; D: col=lane&15, row=quad*4+reg
// MODE 0: bias -> outb (bf16)            MODE 1: bias+GELU -> outb (bf16)
// MODE 2: bias + fp32 x residual, scatter window-reverse+roll(+2) -> outf (fp32 xo)
// MODE 3: bias + fp32 residual (resf) -> outf (fp32, final)
template<int MODE>
__global__ __launch_bounds__(256) void gemm64(
    const u16* __restrict__ A, const u16* __restrict__ BT, const float* __restrict__ bias,
    int K, int N,
    u16* __restrict__ outb, float* __restrict__ outf, const float* __restrict__ resf)
{
  __shared__ u16 As[64*72];   // +8 pad keeps 16B alignment, spreads bank starts
  __shared__ u16 Bs[64*72];
  const int tid = threadIdx.x;
  const int wave = tid >> 6, lane = tid & 63;
  const int quad = lane >> 4, l16 = lane & 15;
  const int m0 = blockIdx.y * 64, n0 = blockIdx.x * 64;

  float4v acc[4];
  #pragma unroll
  for (int i=0;i<4;i++) acc[i] = (float4v){0.f,0.f,0.f,0.f};

  for (int kc = 0; kc < K; kc += 64){
    #pragma unroll
    for (int i=0;i<2;i++){
      int idx = i*256 + tid;          // 512 16B chunks per tile pair
      int row = idx >> 3, cc = idx & 7;
      *(uint4*)(&As[row*72 + cc*8]) = *(const uint4*)(A  + (size_t)(m0+row)*K + kc + cc*8);
      *(uint4*)(&Bs[row*72 + cc*8]) = *(const uint4*)(BT + (size_t)(n0+row)*K + kc + cc*8);
    }
    __syncthreads();
    #pragma unroll
    for (int ks=0; ks<64; ks+=32){
      short8 af = *(const short8*)(&As[(wave*16 + l16)*72 + ks + quad*8]);
      #pragma unroll
      for (int nt=0; nt<4; nt++){
        short8 bfr = *(const short8*)(&Bs[(nt*16 + l16)*72 + ks + quad*8]);
        acc[nt] = __builtin_amdgcn_mfma_f32_16x16x32_bf16(af, bfr, acc[nt], 0, 0, 0);
      }
    }
    __syncthreads();
  }

  #pragma unroll
  for (int nt=0; nt<4; nt++){
    int col = n0 + nt*16 + l16;
    float bv = bias[col];
    #pragma unroll
    for (int r=0;r<4;r++){
      int mrow = m0 + wave*16 + quad*4 + r;
      float v = acc[nt][r] + bv;
      if (MODE == 0){
        outb[(size_t)mrow*N + col] = f2b(v);
      } else if (MODE == 1){
        v = 0.5f*v*(1.0f + erff(v*0.70710678118654752f));  // exact GELU
        outb[(size_t)mrow*N + col] = f2b(v);
      } else if (MODE == 2){
        int win = mrow >> 6, n = mrow & 63;
        int b = win >> 9, rw = win & 511;
        int hs = ((rw>>6)&7)*4 + (n>>4);
        int ws = ((rw>>3)&7)*4 + ((n>>2)&3);
        int ds = (rw&7)*4 + (n&3);
        int h=(hs+2)&31, w=(ws+2)&31, d=(ds+2)&31;       // roll(+2): xo[h]=sx_out[(h-2)%32]
        size_t t = (size_t)((b*32+h)*32+w)*32 + d;
        outf[t*192 + col] = v + resf[t*192 + col];       // + original x (fp32)
      } else {
        outf[(size_t)mrow*192 + col] = v + resf[(size_t)mrow*192 + col];
      }
    }
  }
}

// ---------------- windowed attention: one wave per (window, head) ----------------
__global__ __launch_bounds__(64) void attn_kernel(
    const u16* __restrict__ qkv, const float* __restrict__ bias_table,
    u16* __restrict__ out)
{
  __shared__ float Ksh[64][32];
  __shared__ float Vsh[64][32];
  __shared__ float bsh[343];
  __shared__ int   csh[64];
  const int head = blockIdx.x, win = blockIdx.y;
  const int i = threadIdx.x;

  // cooperative K/V load: 64 rows x 32 cols, 8-elt chunks (256 chunks, 4/thread)
  #pragma unroll
  for (int t=0;t<4;t++){
    int idx = t*64 + i;
    int row = idx >> 2;
    int c0  = (idx & 3) * 8;
    size_t base = ((size_t)win*64 + row)*576 + head*32 + c0;
    union { uint4 v; u16 u[8]; } kk, vv;
    kk.v = *(const uint4*)(qkv + base + 192);
    vv.v = *(const uint4*)(qkv + base + 384);
    #pragma unroll
    for (int e=0;e<8;e++){ Ksh[row][c0+e] = b2f(kk.u[e]); Vsh[row][c0+e] = b2f(vv.u[e]); }
  }
  for (int idx=i; idx<343; idx+=64) bsh[idx] = bias_table[idx*6 + head];

  // shift-mask group (windows on shifted coords; hs=28..29 -> region 1, 30..31 -> region 2)
  int rw = win & 511;
  int bh=(rw>>6)&7, bw=(rw>>3)&7, bd=rw&7;
  int lh=i>>4, lw=(i>>2)&3, ld=i&3;
  int gh = (bh==7) ? (lh<2?1:2) : 0;
  int gw = (bw==7) ? (lw<2?1:2) : 0;
  int gd = (bd==7) ? (ld<2?1:2) : 0;
  csh[i] = gh*9 + gw*3 + gd;

  float q[32];
  {
    size_t base = ((size_t)win*64 + i)*576 + head*32;
    #pragma unroll
    for (int t=0;t<4;t++){
      union { uint4 v; u16 u[8]; } qq;
      qq.v = *(const uint4*)(qkv + base + t*8);
      #pragma unroll
      for (int e=0;e<8;e++) q[t*8+e] = b2f(qq.u[e]);
    }
  }
  __syncthreads();

  float s[64];
  const int ci = csh[i];
  #pragma unroll
  for (int j=0;j<64;j++){
    float a0 = 0.f;
    #pragma unroll
    for (int c=0;c<32;c++) a0 += q[c]*Ksh[j][c];
    int dh = lh-(j>>4)+3, dw = lw-((j>>2)&3)+3, dd = ld-(j&3)+3;
    float sv = a0*0.17677669529663687f + bsh[dh*49 + dw*7 + dd];
    if (csh[j] != ci) sv -= 100.f;
    s[j] = sv;
  }
  float mx = -1e30f;
  #pragma unroll
  for (int j=0;j<64;j++) mx = fmaxf(mx, s[j]);
  float sum = 0.f;
  #pragma unroll
  for (int j=0;j<64;j++){ s[j] = __expf(s[j]-mx); sum += s[j]; }
  float inv = 1.f/sum;
  float o[32];
  #pragma unroll
  for (int c=0;c<32;c++) o[c]=0.f;
  #pragma unroll
  for (int j=0;j<64;j++){
    float p = s[j];
    #pragma unroll
    for (int c=0;c<32;c++) o[c] += p*Vsh[j][c];
  }
  size_t ob = ((size_t)win*64 + i)*192 + head*32;
  #pragma unroll
  for (int c=0;c<32;c++) out[ob+c] = f2b(o[c]*inv);
}

// ---------------- driver ----------------
extern "C" void kernel_launch(void* const* d_in, const int* in_sizes, int n_in,
                              void* d_out, int out_size, void* d_ws, size_t ws_size,
                              hipStream_t stream)
{
  const float* x    = (const float*)d_in[0];
  const float* g1   = (const float*)d_in[1];
  const float* b1   = (const float*)d_in[2];
  const float* wqkv = (const float*)d_in[3];
  const float* bqkv = (const float*)d_in[4];
  const float* wo   = (const float*)d_in[5];
  const float* bo   = (const float*)d_in[6];
  const float* btab = (const float*)d_in[7];
  const float* g2   = (const float*)d_in[8];
  const float* b2v  = (const float*)d_in[9];
  const float* w1   = (const float*)d_in[10];
  const float* bm1  = (const float*)d_in[11];
  const float* w2   = (const float*)d_in[12];
  const float* bm2  = (const float*)d_in[13];
  float* out = (float*)d_out;

  // workspace arena (~97 MB peak):
  // [0, 1.0M)        transposed bf16 weights
  // [1.0M, 26.2M)    xw (LN1+partitioned) -> attn_out -> h1 slice (reused)
  // [26.2M, 101.7M)  qkv (bf16 65536x576); after attention this region is reused:
  //   [26.2M, 76.5M)   xo (fp32 65536x192)
  //   [76.5M, 101.7M)  xn2 (bf16 65536x192)
  char* ws = (char*)d_ws;
  u16*  wqkvT = (u16*)(ws + 0);            // [576][192]
  u16*  woT   = (u16*)(ws + 221184);       // [192][192]
  u16*  w1T   = (u16*)(ws + 294912);       // [768][192]
  u16*  w2T   = (u16*)(ws + 589824);       // [192][768]
  u16*  xw    = (u16*)(ws + 1048576);
  u16*  qkvb  = (u16*)(ws + 26214400);
  float* xo   = (float*)(ws + 26214400);
  u16*  xn2   = (u16*)(ws + 76546048);
  u16*  h1q   = (u16*)(ws + 1048576);      // 16384x768 bf16 slice, overlays dead xw

  transpose_kernel<<<(192*576+255)/256,256,0,stream>>>(wqkv, wqkvT, 192, 576);
  transpose_kernel<<<(192*192+255)/256,256,0,stream>>>(wo,   woT,   192, 192);
  transpose_kernel<<<(192*768+255)/256,256,0,stream>>>(w1,   w1T,   192, 768);
  transpose_kernel<<<(768*192+255)/256,256,0,stream>>>(w2,   w2T,   768, 192);

  // LN1 + shift + window partition  (fp32 x -> bf16 xw)
  ln_kernel<true><<<16384,256,0,stream>>>(x, g1, b1, xw);
  // QKV projection: [65536,192] @ [192,576]
  gemm64<0><<<dim3(9,1024),256,0,stream>>>(xw, wqkvT, bqkv, 192, 576, qkvb, nullptr, nullptr);
  // windowed attention (writes attn_out over xw)
  attn_kernel<<<dim3(6,1024),64,0,stream>>>(qkvb, btab, xw);
  // output projection + window-reverse + unshift + fp32 x residual -> xo (fp32)
  gemm64<2><<<dim3(3,1024),256,0,stream>>>(xw, woT, bo, 192, 192, nullptr, xo, x);
  // LN2 (fp32 xo -> bf16 xn2)
  ln_kernel<false><<<16384,256,0,stream>>>(xo, g2, b2v, xn2);
  // MLP in 4 row-slices of 16384 (h1 slice overlays dead xw region)
  for (int sIdx = 0; sIdx < 4; sIdx++){
    size_t ro = (size_t)sIdx * 16384;
    gemm64<1><<<dim3(12,256),256,0,stream>>>(xn2 + ro*192, w1T, bm1, 192, 768, h1q, nullptr, nullptr);
    gemm64<3><<<dim3(3,256),256,0,stream>>>(h1q, w2T, bm2, 768, 192, nullptr, out + ro*192, xo + ro*192);
  }
}

// Round 3
// 441.408 us; speedup vs baseline: 1.1730x; 1.1730x over previous
//
#include <hip/hip_runtime.h>
#include <math.h>

typedef unsigned short u16;
typedef unsigned int   u32;
using short8  = __attribute__((ext_vector_type(8))) short;
using float4v = __attribute__((ext_vector_type(4))) float;

__device__ __forceinline__ float b2f(u16 u){ return __uint_as_float(((u32)u)<<16); }
__device__ __forceinline__ u16 f2b(float f){
  u32 x = __float_as_uint(f);
  x += 0x7FFFu + ((x>>16)&1u);   // RNE; inputs are tame (no NaN)
  return (u16)(x>>16);
}

// ---------------- weight transpose + fp32->bf16: [R][C] fp32 -> [C][R] bf16 ----------------
__global__ void transpose_kernel(const float* __restrict__ src, u16* __restrict__ dst, int R, int Cc){
  int idx = blockIdx.x*256 + threadIdx.x;
  if (idx < R*Cc){
    int r = idx / Cc, c = idx - r*Cc;
    dst[c*R + r] = f2b(src[idx]);
  }
}

// ---------------- LayerNorm (fp32 in, bf16 out); PART=true: roll(-2) + window partition ----------------
template<bool PART>
__global__ __launch_bounds__(256) void ln_kernel(const float* __restrict__ x,
    const float* __restrict__ g, const float* __restrict__ bvec,
    u16* __restrict__ out)
{
  int wave = threadIdx.x >> 6, lane = threadIdx.x & 63;
  int token = blockIdx.x*4 + wave;          // 0..65535
  int src, dst;
  if (PART){
    int b = token >> 15, r = token & 32767; // token enumerates SHIFTED coords
    int hs = r >> 10, ws = (r >> 5) & 31, ds = r & 31;
    int h = (hs+2)&31, w = (ws+2)&31, d = (ds+2)&31;   // sx[hs] = xn[(hs+2)%32]
    src = ((b*32 + h)*32 + w)*32 + d;
    int win = ((b*8 + (hs>>2))*8 + (ws>>2))*8 + (ds>>2);
    int n   = ((hs&3)*4 + (ws&3))*4 + (ds&3);
    dst = win*64 + n;
  } else { src = token; dst = token; }
  float v[3];
  #pragma unroll
  for (int t=0;t<3;t++) v[t] = x[(size_t)src*192 + lane + t*64];
  float s  = v[0]+v[1]+v[2];
  float s2 = v[0]*v[0]+v[1]*v[1]+v[2]*v[2];
  #pragma unroll
  for (int o=32;o>=1;o>>=1){ s += __shfl_xor(s,o); s2 += __shfl_xor(s2,o); }
  float mean = s*(1.0f/192.0f);
  float var  = s2*(1.0f/192.0f) - mean*mean;
  float rstd = rsqrtf(var + 1e-5f);
  #pragma unroll
  for (int t=0;t<3;t++){
    int c = lane + t*64;
    out[(size_t)dst*192 + c] = f2b((v[t]-mean)*rstd*g[c] + bvec[c]);
  }
}

// ---------------- MFMA GEMM: C[M][N] = A[M][K] @ BT[N][K]^T + bias ----------------
// 64x64 tile, 4 waves, mfma_f32_16x16x32_bf16.
// A frag: m=lane&15, k=quad*8+j ; B frag: n=lane&15, k=quad*8+j ; D: col=lane&15, row=quad*4+reg
// MODE 0: bias -> outb (bf16)            MODE 1: bias+GELU -> outb (bf16)
// MODE 2: bias + fp32 x residual, scatter window-reverse+roll(+2) -> outf (fp32 xo)
// MODE 3: bias + fp32 residual (resf) -> outf (fp32, final)
// MODE 4: like 0 but cols<192 scaled by hd^-0.5 (q-scale folded into QKV proj)
template<int MODE>
__global__ __launch_bounds__(256) void gemm64(
    const u16* __restrict__ A, const u16* __restrict__ BT, const float* __restrict__ bias,
    int K, int N,
    u16* __restrict__ outb, float* __restrict__ outf, const float* __restrict__ resf)
{
  __shared__ u16 As[64*72];   // +8 pad keeps 16B alignment, spreads bank starts
  __shared__ u16 Bs[64*72];
  const int tid = threadIdx.x;
  const int wave = tid >> 6, lane = tid & 63;
  const int quad = lane >> 4, l16 = lane & 15;
  const int m0 = blockIdx.y * 64, n0 = blockIdx.x * 64;

  float4v acc[4];
  #pragma unroll
  for (int i=0;i<4;i++) acc[i] = (float4v){0.f,0.f,0.f,0.f};

  for (int kc = 0; kc < K; kc += 64){
    #pragma unroll
    for (int i=0;i<2;i++){
      int idx = i*256 + tid;          // 512 16B chunks per tile pair
      int row = idx >> 3, cc = idx & 7;
      *(uint4*)(&As[row*72 + cc*8]) = *(const uint4*)(A  + (size_t)(m0+row)*K + kc + cc*8);
      *(uint4*)(&Bs[row*72 + cc*8]) = *(const uint4*)(BT + (size_t)(n0+row)*K + kc + cc*8);
    }
    __syncthreads();
    #pragma unroll
    for (int ks=0; ks<64; ks+=32){
      short8 af = *(const short8*)(&As[(wave*16 + l16)*72 + ks + quad*8]);
      #pragma unroll
      for (int nt=0; nt<4; nt++){
        short8 bfr = *(const short8*)(&Bs[(nt*16 + l16)*72 + ks + quad*8]);
        acc[nt] = __builtin_amdgcn_mfma_f32_16x16x32_bf16(af, bfr, acc[nt], 0, 0, 0);
      }
    }
    __syncthreads();
  }

  #pragma unroll
  for (int nt=0; nt<4; nt++){
    int col = n0 + nt*16 + l16;
    float bv = bias[col];
    #pragma unroll
    for (int r=0;r<4;r++){
      int mrow = m0 + wave*16 + quad*4 + r;
      float v = acc[nt][r] + bv;
      if (MODE == 0 || MODE == 4){
        if (MODE == 4 && col < 192) v *= 0.17677669529663687f;
        outb[(size_t)mrow*N + col] = f2b(v);
      } else if (MODE == 1){
        v = 0.5f*v*(1.0f + erff(v*0.70710678118654752f));  // exact GELU
        outb[(size_t)mrow*N + col] = f2b(v);
      } else if (MODE == 2){
        int win = mrow >> 6, n = mrow & 63;
        int b = win >> 9, rw = win & 511;
        int hs = ((rw>>6)&7)*4 + (n>>4);
        int ws = ((rw>>3)&7)*4 + ((n>>2)&3);
        int ds = (rw&7)*4 + (n&3);
        int h=(hs+2)&31, w=(ws+2)&31, d=(ds+2)&31;       // roll(+2): xo[h]=sx_out[(h-2)%32]
        size_t t = (size_t)((b*32+h)*32+w)*32 + d;
        outf[t*192 + col] = v + resf[t*192 + col];       // + original x (fp32)
      } else {
        outf[(size_t)mrow*192 + col] = v + resf[(size_t)mrow*192 + col];
      }
    }
  }
}

// ---------------- MFMA windowed attention ----------------
// block = 192 threads (3 waves); wave w handles head (blockIdx&1)*3+w of window blockIdx>>1.
// S=QK^T: Q/K fragments loaded directly from global (k contiguous). Softmax in C-layout
// registers (i decomposes as (lh,lw,ld)=(mt,quad,r), j as (nt,l16>>2,l16&3)).
// P stored to LDS with k-swizzle a=(j&15)*4+(j>>4) (b64 packed writes); V^T staged with the
// same swizzle so PV fragments are aligned ds_read_b128. No barriers: waves independent.
__global__ __launch_bounds__(192,3) void attn_mfma(
    const u16* __restrict__ qkv, const float* __restrict__ bias_table,
    u16* __restrict__ out)
{
  __shared__ u16  Psh [3][64*72];
  __shared__ u16  VTsh[3][32*72];
  __shared__ float bsh[3][344];
  const int win  = blockIdx.x >> 1;
  const int wv   = threadIdx.x / 64;
  const int lane = threadIdx.x & 63;
  const int hg   = (blockIdx.x & 1)*3 + wv;
  const int quad = lane >> 4, l16 = lane & 15;

  u16* P  = &Psh[wv][0];
  u16* VT = &VTsh[wv][0];
  float* bs = &bsh[wv][0];
  const u16* base = qkv + (size_t)win*64*576 + hg*32;

  // stage per-head bias table
  for (int idx = lane; idx < 343; idx += 64) bs[idx] = bias_table[idx*6 + hg];

  // stage V^T (swizzled): VT[c][a], a = (j&15)*4 + (j>>4), j = lane
  {
    const int a = (lane & 15)*4 + (lane >> 4);
    #pragma unroll
    for (int t=0;t<4;t++){
      union { uint4 v; u16 u[8]; } vv;
      vv.v = *(const uint4*)(base + (size_t)lane*576 + 384 + t*8);
      #pragma unroll
      for (int e=0;e<8;e++) VT[(t*8+e)*72 + a] = vv.u[e];
    }
  }

  // Q (A-frag) / K (B-frag) direct global loads: 16B each, k = quad*8..+7
  short8 qf[4], kf[4];
  #pragma unroll
  for (int mt=0;mt<4;mt++) qf[mt] = *(const short8*)(base + (size_t)(mt*16 + l16)*576 + quad*8);
  #pragma unroll
  for (int nt=0;nt<4;nt++) kf[nt] = *(const short8*)(base + (size_t)(nt*16 + l16)*576 + 192 + quad*8);

  // S = QK^T (q already scaled by hd^-0.5 in the QKV GEMM epilogue)
  float4v s[4][4];
  #pragma unroll
  for (int mt=0;mt<4;mt++)
    #pragma unroll
    for (int nt=0;nt<4;nt++)
      s[mt][nt] = __builtin_amdgcn_mfma_f32_16x16x32_bf16(qf[mt], kf[nt], (float4v){0.f,0.f,0.f,0.f}, 0,0,0);

  // relative-position bias + shift mask (all register math)
  const int rwn = win & 511;
  const int bh=(rwn>>6)&7, bw=(rwn>>3)&7, bd=rwn&7;
  const int jw = l16>>2, jd = l16&3;
  const int gw_j = (bw==7) ? ((jw  <2)?3:6) : 0;
  const int gd_j = (bd==7) ? ((jd  <2)?1:2) : 0;
  const int gw_i = (bw==7) ? ((quad<2)?3:6) : 0;
  const int laneoff = (quad - jw)*7 - jd + 171;   // center offset 3*49+3*7+3
  #pragma unroll
  for (int mt=0;mt<4;mt++){
    const int gh_i = (bh==7) ? ((mt<2)?9:18) : 0;
    #pragma unroll
    for (int nt=0;nt<4;nt++){
      const int gh_j = (bh==7) ? ((nt<2)?9:18) : 0;
      const int bb = (mt-nt)*49 + laneoff;
      #pragma unroll
      for (int r=0;r<4;r++){
        const int gd_i = (bd==7) ? ((r<2)?1:2) : 0;
        float sv = s[mt][nt][r] + bs[bb + r];
        if ((gh_i + gw_i + gd_i) != (gh_j + gw_j + gd_j)) sv -= 100.f;
        s[mt][nt][r] = sv;
      }
    }
  }

  // row softmax (rows (mt,r) for this lane's quad); normalize P before store
  #pragma unroll
  for (int mt=0;mt<4;mt++){
    #pragma unroll
    for (int r=0;r<4;r++){
      float m0 = fmaxf(fmaxf(s[mt][0][r], s[mt][1][r]), fmaxf(s[mt][2][r], s[mt][3][r]));
      #pragma unroll
      for (int o=8;o>=1;o>>=1) m0 = fmaxf(m0, __shfl_xor(m0,o));
      float sum = 0.f;
      float e[4];
      #pragma unroll
      for (int nt=0;nt<4;nt++){ e[nt] = __expf(s[mt][nt][r] - m0); sum += e[nt]; }
      #pragma unroll
      for (int o=8;o>=1;o>>=1) sum += __shfl_xor(sum,o);
      const float rinv = 1.f/sum;
      union { unsigned long long d; u16 u[4]; } pk;
      #pragma unroll
      for (int nt=0;nt<4;nt++) pk.u[nt] = f2b(e[nt]*rinv);
      *(unsigned long long*)(&P[(mt*16 + quad*4 + r)*72 + l16*4]) = pk.d;  // swizzled a=l16*4+nt
    }
  }

  // out = P @ V  (both operands in swizzled-j order; dot is order-invariant)
  float4v o2[4][2];
  #pragma unroll
  for (int mt=0;mt<4;mt++){ o2[mt][0]=(float4v){0.f,0.f,0.f,0.f}; o2[mt][1]=(float4v){0.f,0.f,0.f,0.f}; }
  #pragma unroll
  for (int s2=0;s2<2;s2++){
    short8 vfrag[2];
    #pragma unroll
    for (int ct=0;ct<2;ct++) vfrag[ct] = *(const short8*)(&VT[(ct*16 + l16)*72 + s2*32 + quad*8]);
    #pragma unroll
    for (int mt=0;mt<4;mt++){
      short8 pfrag = *(const short8*)(&P[(mt*16 + l16)*72 + s2*32 + quad*8]);
      #pragma unroll
      for (int ct=0;ct<2;ct++)
        o2[mt][ct] = __builtin_amdgcn_mfma_f32_16x16x32_bf16(pfrag, vfrag[ct], o2[mt][ct], 0,0,0);
    }
  }

  #pragma unroll
  for (int mt=0;mt<4;mt++)
    #pragma unroll
    for (int ct=0;ct<2;ct++)
      #pragma unroll
      for (int r=0;r<4;r++){
        int i = mt*16 + quad*4 + r;
        out[((size_t)win*64 + i)*192 + hg*32 + ct*16 + l16] = f2b(o2[mt][ct][r]);
      }
}

// ---------------- driver ----------------
extern "C" void kernel_launch(void* const* d_in, const int* in_sizes, int n_in,
                              void* d_out, int out_size, void* d_ws, size_t ws_size,
                              hipStream_t stream)
{
  const float* x    = (const float*)d_in[0];
  const float* g1   = (const float*)d_in[1];
  const float* b1   = (const float*)d_in[2];
  const float* wqkv = (const float*)d_in[3];
  const float* bqkv = (const float*)d_in[4];
  const float* wo   = (const float*)d_in[5];
  const float* bo   = (const float*)d_in[6];
  const float* btab = (const float*)d_in[7];
  const float* g2   = (const float*)d_in[8];
  const float* b2v  = (const float*)d_in[9];
  const float* w1   = (const float*)d_in[10];
  const float* bm1  = (const float*)d_in[11];
  const float* w2   = (const float*)d_in[12];
  const float* bm2  = (const float*)d_in[13];
  float* out = (float*)d_out;

  // workspace arena (~97 MB peak) — see round-1 comments
  char* ws = (char*)d_ws;
  u16*  wqkvT = (u16*)(ws + 0);            // [576][192]
  u16*  woT   = (u16*)(ws + 221184);       // [192][192]
  u16*  w1T   = (u16*)(ws + 294912);       // [768][192]
  u16*  w2T   = (u16*)(ws + 589824);       // [192][768]
  u16*  xw    = (u16*)(ws + 1048576);
  u16*  qkvb  = (u16*)(ws + 26214400);
  float* xo   = (float*)(ws + 26214400);
  u16*  xn2   = (u16*)(ws + 76546048);
  u16*  h1q   = (u16*)(ws + 1048576);      // 16384x768 bf16 slice, overlays dead xw

  transpose_kernel<<<(192*576+255)/256,256,0,stream>>>(wqkv, wqkvT, 192, 576);
  transpose_kernel<<<(192*192+255)/256,256,0,stream>>>(wo,   woT,   192, 192);
  transpose_kernel<<<(192*768+255)/256,256,0,stream>>>(w1,   w1T,   192, 768);
  transpose_kernel<<<(768*192+255)/256,256,0,stream>>>(w2,   w2T,   768, 192);

  // LN1 + shift + window partition  (fp32 x -> bf16 xw)
  ln_kernel<true><<<16384,256,0,stream>>>(x, g1, b1, xw);
  // QKV projection (+ q-scale): [65536,192] @ [192,576]
  gemm64<4><<<dim3(9,1024),256,0,stream>>>(xw, wqkvT, bqkv, 192, 576, qkvb, nullptr, nullptr);
  // MFMA windowed attention (writes attn_out over xw)
  attn_mfma<<<2048,192,0,stream>>>(qkvb, btab, xw);
  // output projection + window-reverse + unshift + fp32 x residual -> xo (fp32)
  gemm64<2><<<dim3(3,1024),256,0,stream>>>(xw, woT, bo, 192, 192, nullptr, xo, x);
  // LN2 (fp32 xo -> bf16 xn2)
  ln_kernel<false><<<16384,256,0,stream>>>(xo, g2, b2v, xn2);
  // MLP in 4 row-slices of 16384 (h1 slice overlays dead xw region)
  for (int sIdx = 0; sIdx < 4; sIdx++){
    size_t ro = (size_t)sIdx * 16384;
    gemm64<1><<<dim3(12,256),256,0,stream>>>(xn2 + ro*192, w1T, bm1, 192, 768, h1q, nullptr, nullptr);
    gemm64<3><<<dim3(3,256),256,0,stream>>>(h1q, w2T, bm2, 768, 192, nullptr, out + ro*192, xo + ro*192);
  }
}

// Round 4
// 404.834 us; speedup vs baseline: 1.2790x; 1.0903x over previous
//
#include <hip/hip_runtime.h>
#include <math.h>

typedef unsigned short u16;
typedef unsigned int   u32;
using short8  = __attribute__((ext_vector_type(8))) short;
using float4v = __attribute__((ext_vector_type(4))) float;

__device__ __forceinline__ float b2f(u16 u){ return __uint_as_float(((u32)u)<<16); }
__device__ __forceinline__ u16 f2b(float f){
  u32 x = __float_as_uint(f);
  x += 0x7FFFu + ((x>>16)&1u);   // RNE; inputs are tame (no NaN)
  return (u16)(x>>16);
}

// async global->LDS, 16B per lane. LDS dest = wave-uniform base + lane*16.
__device__ __forceinline__ void gload_lds16(const u16* g, u16* l){
  __builtin_amdgcn_global_load_lds((const __attribute__((address_space(1))) void*)g,
                                   (__attribute__((address_space(3))) void*)l, 16, 0, 0);
}

// ---------------- all 4 weight transposes (+fp32->bf16) in one launch ----------------
__global__ void transpose_all(const float* __restrict__ wqkv, const float* __restrict__ wo,
                              const float* __restrict__ w1,   const float* __restrict__ w2,
                              u16* __restrict__ wqkvT, u16* __restrict__ woT,
                              u16* __restrict__ w1T,   u16* __restrict__ w2T){
  int idx = blockIdx.x*256 + threadIdx.x;
  if (idx < 110592){ int r=idx/576, c=idx-r*576; wqkvT[c*192+r]=f2b(wqkv[idx]); }
  else if (idx < 147456){ int j=idx-110592; int r=j/192, c=j-r*192; woT[c*192+r]=f2b(wo[j]); }
  else if (idx < 294912){ int j=idx-147456; int r=j/768, c=j-r*768; w1T[c*192+r]=f2b(w1[j]); }
  else if (idx < 442368){ int j=idx-294912; int r=j/192, c=j-r*192; w2T[c*768+r]=f2b(w2[j]); }
}

// ---------------- LayerNorm (fp32 in, bf16 out); PART=true: roll(-2) + window partition ----------------
template<bool PART>
__global__ __launch_bounds__(256) void ln_kernel(const float* __restrict__ x,
    const float* __restrict__ g, const float* __restrict__ bvec,
    u16* __restrict__ out)
{
  int wave = threadIdx.x >> 6, lane = threadIdx.x & 63;
  int token = blockIdx.x*4 + wave;          // 0..65535
  int src, dst;
  if (PART){
    int b = token >> 15, r = token & 32767; // token enumerates SHIFTED coords
    int hs = r >> 10, ws = (r >> 5) & 31, ds = r & 31;
    int h = (hs+2)&31, w = (ws+2)&31, d = (ds+2)&31;   // sx[hs] = xn[(hs+2)%32]
    src = ((b*32 + h)*32 + w)*32 + d;
    int win = ((b*8 + (hs>>2))*8 + (ws>>2))*8 + (ds>>2);
    int n   = ((hs&3)*4 + (ws&3))*4 + (ds&3);
    dst = win*64 + n;
  } else { src = token; dst = token; }
  float v[3];
  #pragma unroll
  for (int t=0;t<3;t++) v[t] = x[(size_t)src*192 + lane + t*64];
  float s  = v[0]+v[1]+v[2];
  float s2 = v[0]*v[0]+v[1]*v[1]+v[2]*v[2];
  #pragma unroll
  for (int o=32;o>=1;o>>=1){ s += __shfl_xor(s,o); s2 += __shfl_xor(s2,o); }
  float mean = s*(1.0f/192.0f);
  float var  = s2*(1.0f/192.0f) - mean*mean;
  float rstd = rsqrtf(var + 1e-5f);
  #pragma unroll
  for (int t=0;t<3;t++){
    int c = lane + t*64;
    out[(size_t)dst*192 + c] = f2b((v[t]-mean)*rstd*g[c] + bvec[c]);
  }
}

// ---------------- MFMA GEMM, m97-class: C[M][N] = A[M][K] @ BT[N][K]^T + bias ----------------
// Block = (WAVES*64) x 64 output; each wave owns a 64x64 tile (4x4 of 16x16x32 mfma):
// 16 MFMA per 8 ds_read_b128 per ks-step. Staging via global_load_lds width 16
// (LDS layout [rows][64] unpadded, as the DMA requires).
// MODE 0: bias -> outb     MODE 1: bias+GELU -> outb
// MODE 2: bias + fp32 x residual, scatter window-reverse+roll(+2) -> outf (fp32 xo)
// MODE 3: bias + fp32 residual -> outf (fp32, final)
// MODE 4: bias, cols<192 scaled by hd^-0.5 (q-scale folded into QKV proj)
template<int MODE, int WAVES>
__global__ __launch_bounds__(WAVES*64) void gemm_big(
    const u16* __restrict__ A, const u16* __restrict__ BT, const float* __restrict__ bias,
    int K, int N,
    u16* __restrict__ outb, float* __restrict__ outf, const float* __restrict__ resf)
{
  constexpr int BM = WAVES*64;
  __shared__ u16 As[BM*64];
  __shared__ u16 Bs[64*64];
  const int tid = threadIdx.x;
  const int wv = tid >> 6, lane = tid & 63;
  const int quad = lane >> 4, l16 = lane & 15;
  const int m0 = blockIdx.y * BM, n0 = blockIdx.x * 64;

  float4v acc[16];
  #pragma unroll
  for (int i=0;i<16;i++) acc[i] = (float4v){0.f,0.f,0.f,0.f};

  for (int kc = 0; kc < K; kc += 64){
    #pragma unroll
    for (int t=0;t<8;t++){            // A: BM*8 chunks of 16B
      int chunk = (wv*8+t)*64 + lane;
      gload_lds16(A + (size_t)(m0 + (chunk>>3))*K + kc + (chunk&7)*8,
                  As + (wv*8+t)*512);
    }
    #pragma unroll
    for (int t=0;t<8/WAVES;t++){      // B: 512 chunks of 16B
      int chunk = (wv*(8/WAVES)+t)*64 + lane;
      gload_lds16(BT + (size_t)(n0 + (chunk>>3))*K + kc + (chunk&7)*8,
                  Bs + (wv*(8/WAVES)+t)*512);
    }
    __syncthreads();
    const u16* Aw = As + wv*64*64;
    #pragma unroll
    for (int ks=0; ks<2; ks++){
      short8 af[4], bfr[4];
      #pragma unroll
      for (int mt=0;mt<4;mt++) af[mt]  = *(const short8*)(Aw + (mt*16+l16)*64 + ks*32 + quad*8);
      #pragma unroll
      for (int nt=0;nt<4;nt++) bfr[nt] = *(const short8*)(Bs + (nt*16+l16)*64 + ks*32 + quad*8);
      #pragma unroll
      for (int mt=0;mt<4;mt++)
        #pragma unroll
        for (int nt=0;nt<4;nt++)
          acc[mt*4+nt] = __builtin_amdgcn_mfma_f32_16x16x32_bf16(af[mt], bfr[nt], acc[mt*4+nt], 0,0,0);
    }
    __syncthreads();
  }

  #pragma unroll
  for (int nt=0;nt<4;nt++){
    int col = n0 + nt*16 + l16;
    float bv = bias[col];
    #pragma unroll
    for (int mt=0;mt<4;mt++){
      float4v a = acc[mt*4+nt];
      #pragma unroll
      for (int r=0;r<4;r++){
        int mrow = m0 + wv*64 + mt*16 + quad*4 + r;
        float v = a[r] + bv;
        if (MODE == 0 || MODE == 4){
          if (MODE == 4 && col < 192) v *= 0.17677669529663687f;
          outb[(size_t)mrow*N + col] = f2b(v);
        } else if (MODE == 1){
          v = 0.5f*v*(1.0f + erff(v*0.70710678118654752f));  // exact GELU
          outb[(size_t)mrow*N + col] = f2b(v);
        } else if (MODE == 2){
          int win = mrow >> 6, n = mrow & 63;
          int b = win >> 9, rw = win & 511;
          int hs = ((rw>>6)&7)*4 + (n>>4);
          int ws = ((rw>>3)&7)*4 + ((n>>2)&3);
          int ds = (rw&7)*4 + (n&3);
          int h=(hs+2)&31, w=(ws+2)&31, d=(ds+2)&31;       // roll(+2)
          size_t t = (size_t)((b*32+h)*32+w)*32 + d;
          outf[t*192 + col] = v + resf[t*192 + col];       // + original x (fp32)
        } else {
          outf[(size_t)mrow*192 + col] = v + resf[(size_t)mrow*192 + col];
        }
      }
    }
  }
}

// ---------------- MFMA windowed attention (unchanged from round 3) ----------------
__global__ __launch_bounds__(192,3) void attn_mfma(
    const u16* __restrict__ qkv, const float* __restrict__ bias_table,
    u16* __restrict__ out)
{
  __shared__ u16  Psh [3][64*72];
  __shared__ u16  VTsh[3][32*72];
  __shared__ float bsh[3][344];
  const int win  = blockIdx.x >> 1;
  const int wv   = threadIdx.x / 64;
  const int lane = threadIdx.x & 63;
  const int hg   = (blockIdx.x & 1)*3 + wv;
  const int quad = lane >> 4, l16 = lane & 15;

  u16* P  = &Psh[wv][0];
  u16* VT = &VTsh[wv][0];
  float* bs = &bsh[wv][0];
  const u16* base = qkv + (size_t)win*64*576 + hg*32;

  for (int idx = lane; idx < 343; idx += 64) bs[idx] = bias_table[idx*6 + hg];

  {
    const int a = (lane & 15)*4 + (lane >> 4);
    #pragma unroll
    for (int t=0;t<4;t++){
      union { uint4 v; u16 u[8]; } vv;
      vv.v = *(const uint4*)(base + (size_t)lane*576 + 384 + t*8);
      #pragma unroll
      for (int e=0;e<8;e++) VT[(t*8+e)*72 + a] = vv.u[e];
    }
  }

  short8 qf[4], kf[4];
  #pragma unroll
  for (int mt=0;mt<4;mt++) qf[mt] = *(const short8*)(base + (size_t)(mt*16 + l16)*576 + quad*8);
  #pragma unroll
  for (int nt=0;nt<4;nt++) kf[nt] = *(const short8*)(base + (size_t)(nt*16 + l16)*576 + 192 + quad*8);

  float4v s[4][4];
  #pragma unroll
  for (int mt=0;mt<4;mt++)
    #pragma unroll
    for (int nt=0;nt<4;nt++)
      s[mt][nt] = __builtin_amdgcn_mfma_f32_16x16x32_bf16(qf[mt], kf[nt], (float4v){0.f,0.f,0.f,0.f}, 0,0,0);

  const int rwn = win & 511;
  const int bh=(rwn>>6)&7, bw=(rwn>>3)&7, bd=rwn&7;
  const int jw = l16>>2, jd = l16&3;
  const int gw_j = (bw==7) ? ((jw  <2)?3:6) : 0;
  const int gd_j = (bd==7) ? ((jd  <2)?1:2) : 0;
  const int gw_i = (bw==7) ? ((quad<2)?3:6) : 0;
  const int laneoff = (quad - jw)*7 - jd + 171;
  #pragma unroll
  for (int mt=0;mt<4;mt++){
    const int gh_i = (bh==7) ? ((mt<2)?9:18) : 0;
    #pragma unroll
    for (int nt=0;nt<4;nt++){
      const int gh_j = (bh==7) ? ((nt<2)?9:18) : 0;
      const int bb = (mt-nt)*49 + laneoff;
      #pragma unroll
      for (int r=0;r<4;r++){
        const int gd_i = (bd==7) ? ((r<2)?1:2) : 0;
        float sv = s[mt][nt][r] + bs[bb + r];
        if ((gh_i + gw_i + gd_i) != (gh_j + gw_j + gd_j)) sv -= 100.f;
        s[mt][nt][r] = sv;
      }
    }
  }

  #pragma unroll
  for (int mt=0;mt<4;mt++){
    #pragma unroll
    for (int r=0;r<4;r++){
      float m0 = fmaxf(fmaxf(s[mt][0][r], s[mt][1][r]), fmaxf(s[mt][2][r], s[mt][3][r]));
      #pragma unroll
      for (int o=8;o>=1;o>>=1) m0 = fmaxf(m0, __shfl_xor(m0,o));
      float sum = 0.f;
      float e[4];
      #pragma unroll
      for (int nt=0;nt<4;nt++){ e[nt] = __expf(s[mt][nt][r] - m0); sum += e[nt]; }
      #pragma unroll
      for (int o=8;o>=1;o>>=1) sum += __shfl_xor(sum,o);
      const float rinv = 1.f/sum;
      union { unsigned long long d; u16 u[4]; } pk;
      #pragma unroll
      for (int nt=0;nt<4;nt++) pk.u[nt] = f2b(e[nt]*rinv);
      *(unsigned long long*)(&P[(mt*16 + quad*4 + r)*72 + l16*4]) = pk.d;
    }
  }

  float4v o2[4][2];
  #pragma unroll
  for (int mt=0;mt<4;mt++){ o2[mt][0]=(float4v){0.f,0.f,0.f,0.f}; o2[mt][1]=(float4v){0.f,0.f,0.f,0.f}; }
  #pragma unroll
  for (int s2=0;s2<2;s2++){
    short8 vfrag[2];
    #pragma unroll
    for (int ct=0;ct<2;ct++) vfrag[ct] = *(const short8*)(&VT[(ct*16 + l16)*72 + s2*32 + quad*8]);
    #pragma unroll
    for (int mt=0;mt<4;mt++){
      short8 pfrag = *(const short8*)(&P[(mt*16 + l16)*72 + s2*32 + quad*8]);
      #pragma unroll
      for (int ct=0;ct<2;ct++)
        o2[mt][ct] = __builtin_amdgcn_mfma_f32_16x16x32_bf16(pfrag, vfrag[ct], o2[mt][ct], 0,0,0);
    }
  }

  #pragma unroll
  for (int mt=0;mt<4;mt++)
    #pragma unroll
    for (int ct=0;ct<2;ct++)
      #pragma unroll
      for (int r=0;r<4;r++){
        int i = mt*16 + quad*4 + r;
        out[((size_t)win*64 + i)*192 + hg*32 + ct*16 + l16] = f2b(o2[mt][ct][r]);
      }
}

// ---------------- driver ----------------
extern "C" void kernel_launch(void* const* d_in, const int* in_sizes, int n_in,
                              void* d_out, int out_size, void* d_ws, size_t ws_size,
                              hipStream_t stream)
{
  const float* x    = (const float*)d_in[0];
  const float* g1   = (const float*)d_in[1];
  const float* b1   = (const float*)d_in[2];
  const float* wqkv = (const float*)d_in[3];
  const float* bqkv = (const float*)d_in[4];
  const float* wo   = (const float*)d_in[5];
  const float* bo   = (const float*)d_in[6];
  const float* btab = (const float*)d_in[7];
  const float* g2   = (const float*)d_in[8];
  const float* b2v  = (const float*)d_in[9];
  const float* w1   = (const float*)d_in[10];
  const float* bm1  = (const float*)d_in[11];
  const float* w2   = (const float*)d_in[12];
  const float* bm2  = (const float*)d_in[13];
  float* out = (float*)d_out;

  char* ws = (char*)d_ws;
  u16*  wqkvT = (u16*)(ws + 0);            // [576][192]
  u16*  woT   = (u16*)(ws + 221184);       // [192][192]
  u16*  w1T   = (u16*)(ws + 294912);       // [768][192]
  u16*  w2T   = (u16*)(ws + 589824);       // [192][768]
  u16*  xw    = (u16*)(ws + 1048576);      // 65536x192 bf16
  u16*  qkvb  = (u16*)(ws + 26214400);     // 65536x576 bf16 (dead after attn)
  float* xo   = (float*)(ws + 26214400);   // 65536x192 fp32 (overlays dead qkv)
  u16*  xn2   = (u16*)(ws + 76546048);     // 65536x192 bf16
  // MLP h1: 2 slices at top of arena if ws allows, else 4 slices overlaying dead xw
  int nslice; u16* h1s;
  if (ws_size >= (size_t)160000000){ nslice = 2; h1s = (u16*)(ws + 101711872); }
  else                              { nslice = 4; h1s = xw; }

  transpose_all<<<1728,256,0,stream>>>(wqkv, wo, w1, w2, wqkvT, woT, w1T, w2T);

  // LN1 + shift + window partition  (fp32 x -> bf16 xw)
  ln_kernel<true><<<16384,256,0,stream>>>(x, g1, b1, xw);
  // QKV projection (+ q-scale): [65536,192] @ [192,576]
  gemm_big<4,4><<<dim3(9,256),256,0,stream>>>(xw, wqkvT, bqkv, 192, 576, qkvb, nullptr, nullptr);
  // MFMA windowed attention (writes attn_out over xw)
  attn_mfma<<<2048,192,0,stream>>>(qkvb, btab, xw);
  // output projection + window-reverse + unshift + fp32 x residual -> xo (fp32)
  gemm_big<2,2><<<dim3(3,512),128,0,stream>>>(xw, woT, bo, 192, 192, nullptr, xo, x);
  // LN2 (fp32 xo -> bf16 xn2)
  ln_kernel<false><<<16384,256,0,stream>>>(xo, g2, b2v, xn2);
  // MLP in slices
  const int rows = 65536 / nslice;
  for (int sIdx = 0; sIdx < nslice; sIdx++){
    size_t ro = (size_t)sIdx * rows;
    gemm_big<1,4><<<dim3(12,rows/256),256,0,stream>>>(xn2 + ro*192, w1T, bm1, 192, 768, h1s, nullptr, nullptr);
    gemm_big<3,2><<<dim3(3,rows/128),128,0,stream>>>(h1s, w2T, bm2, 768, 192, nullptr, out + ro*192, xo + ro*192);
  }
}

// Round 5
// 376.644 us; speedup vs baseline: 1.3747x; 1.0748x over previous
//
#include <hip/hip_runtime.h>
#include <math.h>

typedef unsigned short u16;
typedef unsigned int   u32;
using short8  = __attribute__((ext_vector_type(8))) short;
using float4v = __attribute__((ext_vector_type(4))) float;

__device__ __forceinline__ float b2f(u16 u){ return __uint_as_float(((u32)u)<<16); }
__device__ __forceinline__ u16 f2b(float f){
  u32 x = __float_as_uint(f);
  x += 0x7FFFu + ((x>>16)&1u);   // RNE; inputs are tame (no NaN)
  return (u16)(x>>16);
}

// async global->LDS, 16B per lane. LDS dest = wave-uniform base + lane*16.
__device__ __forceinline__ void gload_lds16(const u16* g, u16* l){
  __builtin_amdgcn_global_load_lds((const __attribute__((address_space(1))) void*)g,
                                   (__attribute__((address_space(3))) void*)l, 16, 0, 0);
}

// ---------------- all 4 weight transposes (+fp32->bf16) in one launch ----------------
__global__ void transpose_all(const float* __restrict__ wqkv, const float* __restrict__ wo,
                              const float* __restrict__ w1,   const float* __restrict__ w2,
                              u16* __restrict__ wqkvT, u16* __restrict__ woT,
                              u16* __restrict__ w1T,   u16* __restrict__ w2T){
  int idx = blockIdx.x*256 + threadIdx.x;
  if (idx < 110592){ int r=idx/576, c=idx-r*576; wqkvT[c*192+r]=f2b(wqkv[idx]); }
  else if (idx < 147456){ int j=idx-110592; int r=j/192, c=j-r*192; woT[c*192+r]=f2b(wo[j]); }
  else if (idx < 294912){ int j=idx-147456; int r=j/768, c=j-r*768; w1T[c*192+r]=f2b(w1[j]); }
  else if (idx < 442368){ int j=idx-294912; int r=j/192, c=j-r*192; w2T[c*768+r]=f2b(w2[j]); }
}

// ---------------- LayerNorm (fp32 in, bf16 out); PART=true: roll(-2) + window partition ----------------
template<bool PART>
__global__ __launch_bounds__(256) void ln_kernel(const float* __restrict__ x,
    const float* __restrict__ g, const float* __restrict__ bvec,
    u16* __restrict__ out)
{
  int wave = threadIdx.x >> 6, lane = threadIdx.x & 63;
  int token = blockIdx.x*4 + wave;          // 0..65535
  int src, dst;
  if (PART){
    int b = token >> 15, r = token & 32767; // token enumerates SHIFTED coords
    int hs = r >> 10, ws = (r >> 5) & 31, ds = r & 31;
    int h = (hs+2)&31, w = (ws+2)&31, d = (ds+2)&31;   // sx[hs] = xn[(hs+2)%32]
    src = ((b*32 + h)*32 + w)*32 + d;
    int win = ((b*8 + (hs>>2))*8 + (ws>>2))*8 + (ds>>2);
    int n   = ((hs&3)*4 + (ws&3))*4 + (ds&3);
    dst = win*64 + n;
  } else { src = token; dst = token; }
  float v[3];
  #pragma unroll
  for (int t=0;t<3;t++) v[t] = x[(size_t)src*192 + lane + t*64];
  float s  = v[0]+v[1]+v[2];
  float s2 = v[0]*v[0]+v[1]*v[1]+v[2]*v[2];
  #pragma unroll
  for (int o=32;o>=1;o>>=1){ s += __shfl_xor(s,o); s2 += __shfl_xor(s2,o); }
  float mean = s*(1.0f/192.0f);
  float var  = s2*(1.0f/192.0f) - mean*mean;
  float rstd = rsqrtf(var + 1e-5f);
  #pragma unroll
  for (int t=0;t<3;t++){
    int c = lane + t*64;
    out[(size_t)dst*192 + c] = f2b((v[t]-mean)*rstd*g[c] + bvec[c]);
  }
}

// ---------------- MFMA GEMM, full-K-chunk (BK=192): C = A[M][K] @ BT[N][K]^T + bias ----------------
// 64x64 block, 4 waves each computing a 32x32 tile. For K=192 there is exactly ONE
// load->barrier->compute pass (no K-loop drain); K=768 does 4 passes.
// LDS layout: 16B chunk (g,row,c3) at elem offset g*4096 + row*64 + c3*8, where the
// stored chunk is G[row][g*8 + (c3 ^ (row&7))] — XOR swizzle keeps global_load_lds
// lane-contiguous (8 rows x 128B per instr, perfectly coalesced) AND makes fragment
// ds_read_b128 2-way-conflict-only (free, m136).
// MODE 0: bias->outb  1: bias+GELU->outb  2: bias+x-residual scatter->outf
// MODE 3: bias+resf->outf (final)         4: bias, cols<192 scaled by hd^-0.5
template<int MODE>
__global__ __launch_bounds__(256) void gemm_fk(
    const u16* __restrict__ A, const u16* __restrict__ BT, const float* __restrict__ bias,
    const int K, const int N,
    u16* __restrict__ outb, float* __restrict__ outf, const float* __restrict__ resf)
{
  __shared__ u16 As[64*192];   // 24 KB
  __shared__ u16 Bs[64*192];   // 24 KB
  const int tid = threadIdx.x;
  const int wv = tid >> 6, lane = tid & 63;
  const int quad = lane >> 4, l16 = lane & 15;
  const int m0 = blockIdx.y * 64, n0 = blockIdx.x * 64;
  const int wm = (wv >> 1) * 32, wn = (wv & 1) * 32;   // wave's 32x32 tile

  float4v acc[2][2];
  #pragma unroll
  for (int a=0;a<2;a++) for (int b=0;b<2;b++) acc[a][b] = (float4v){0.f,0.f,0.f,0.f};

  const int srow8 = lane >> 3;             // row within octet
  const int scc   = (lane & 7) ^ srow8;    // swizzled source chunk within 128B group
  const int c3x   = l16 & 7;               // fragment-read swizzle phase

  for (int kc = 0; kc < K; kc += 192){
    #pragma unroll
    for (int t=0;t<6;t++){
      int ig = wv*6 + t;                   // 0..23 : (group g, row-octet ro)
      int g = ig >> 3, ro = ig & 7;
      int row = ro*8 + srow8;
      gload_lds16(A  + (size_t)(m0+row)*K + kc + g*64 + scc*8, As + g*4096 + ro*512);
      gload_lds16(BT + (size_t)(n0+row)*K + kc + g*64 + scc*8, Bs + g*4096 + ro*512);
    }
    __syncthreads();
    #pragma unroll
    for (int ks=0; ks<6; ks++){
      const int cc = ks*4 + quad, g = cc >> 3, c3 = (cc & 7) ^ c3x;
      short8 af[2], bf2[2];
      #pragma unroll
      for (int mt=0;mt<2;mt++) af[mt]  = *(const short8*)(As + g*4096 + (wm+mt*16+l16)*64 + c3*8);
      #pragma unroll
      for (int nt=0;nt<2;nt++) bf2[nt] = *(const short8*)(Bs + g*4096 + (wn+nt*16+l16)*64 + c3*8);
      #pragma unroll
      for (int mt=0;mt<2;mt++)
        #pragma unroll
        for (int nt=0;nt<2;nt++)
          acc[mt][nt] = __builtin_amdgcn_mfma_f32_16x16x32_bf16(af[mt], bf2[nt], acc[mt][nt], 0,0,0);
    }
    if (kc + 192 < K) __syncthreads();
  }

  #pragma unroll
  for (int nt=0;nt<2;nt++){
    int col = n0 + wn + nt*16 + l16;
    float bv = bias[col];
    #pragma unroll
    for (int mt=0;mt<2;mt++){
      float4v a = acc[mt][nt];
      #pragma unroll
      for (int r=0;r<4;r++){
        int mrow = m0 + wm + mt*16 + quad*4 + r;
        float v = a[r] + bv;
        if (MODE == 0 || MODE == 4){
          if (MODE == 4 && col < 192) v *= 0.17677669529663687f;
          outb[(size_t)mrow*N + col] = f2b(v);
        } else if (MODE == 1){
          v = 0.5f*v*(1.0f + erff(v*0.70710678118654752f));  // exact GELU
          outb[(size_t)mrow*N + col] = f2b(v);
        } else if (MODE == 2){
          int win = mrow >> 6, n = mrow & 63;
          int b = win >> 9, rw = win & 511;
          int hs = ((rw>>6)&7)*4 + (n>>4);
          int ws = ((rw>>3)&7)*4 + ((n>>2)&3);
          int ds = (rw&7)*4 + (n&3);
          int h=(hs+2)&31, w=(ws+2)&31, d=(ds+2)&31;       // roll(+2)
          size_t t = (size_t)((b*32+h)*32+w)*32 + d;
          outf[t*192 + col] = v + resf[t*192 + col];       // + original x (fp32)
        } else {
          outf[(size_t)mrow*192 + col] = v + resf[(size_t)mrow*192 + col];
        }
      }
    }
  }
}

// ---------------- MFMA windowed attention (unchanged) ----------------
__global__ __launch_bounds__(192,3) void attn_mfma(
    const u16* __restrict__ qkv, const float* __restrict__ bias_table,
    u16* __restrict__ out)
{
  __shared__ u16  Psh [3][64*72];
  __shared__ u16  VTsh[3][32*72];
  __shared__ float bsh[3][344];
  const int win  = blockIdx.x >> 1;
  const int wv   = threadIdx.x / 64;
  const int lane = threadIdx.x & 63;
  const int hg   = (blockIdx.x & 1)*3 + wv;
  const int quad = lane >> 4, l16 = lane & 15;

  u16* P  = &Psh[wv][0];
  u16* VT = &VTsh[wv][0];
  float* bs = &bsh[wv][0];
  const u16* base = qkv + (size_t)win*64*576 + hg*32;

  for (int idx = lane; idx < 343; idx += 64) bs[idx] = bias_table[idx*6 + hg];

  {
    const int a = (lane & 15)*4 + (lane >> 4);
    #pragma unroll
    for (int t=0;t<4;t++){
      union { uint4 v; u16 u[8]; } vv;
      vv.v = *(const uint4*)(base + (size_t)lane*576 + 384 + t*8);
      #pragma unroll
      for (int e=0;e<8;e++) VT[(t*8+e)*72 + a] = vv.u[e];
    }
  }

  short8 qf[4], kf[4];
  #pragma unroll
  for (int mt=0;mt<4;mt++) qf[mt] = *(const short8*)(base + (size_t)(mt*16 + l16)*576 + quad*8);
  #pragma unroll
  for (int nt=0;nt<4;nt++) kf[nt] = *(const short8*)(base + (size_t)(nt*16 + l16)*576 + 192 + quad*8);

  float4v s[4][4];
  #pragma unroll
  for (int mt=0;mt<4;mt++)
    #pragma unroll
    for (int nt=0;nt<4;nt++)
      s[mt][nt] = __builtin_amdgcn_mfma_f32_16x16x32_bf16(qf[mt], kf[nt], (float4v){0.f,0.f,0.f,0.f}, 0,0,0);

  const int rwn = win & 511;
  const int bh=(rwn>>6)&7, bw=(rwn>>3)&7, bd=rwn&7;
  const int jw = l16>>2, jd = l16&3;
  const int gw_j = (bw==7) ? ((jw  <2)?3:6) : 0;
  const int gd_j = (bd==7) ? ((jd  <2)?1:2) : 0;
  const int gw_i = (bw==7) ? ((quad<2)?3:6) : 0;
  const int laneoff = (quad - jw)*7 - jd + 171;
  #pragma unroll
  for (int mt=0;mt<4;mt++){
    const int gh_i = (bh==7) ? ((mt<2)?9:18) : 0;
    #pragma unroll
    for (int nt=0;nt<4;nt++){
      const int gh_j = (bh==7) ? ((nt<2)?9:18) : 0;
      const int bb = (mt-nt)*49 + laneoff;
      #pragma unroll
      for (int r=0;r<4;r++){
        const int gd_i = (bd==7) ? ((r<2)?1:2) : 0;
        float sv = s[mt][nt][r] + bs[bb + r];
        if ((gh_i + gw_i + gd_i) != (gh_j + gw_j + gd_j)) sv -= 100.f;
        s[mt][nt][r] = sv;
      }
    }
  }

  #pragma unroll
  for (int mt=0;mt<4;mt++){
    #pragma unroll
    for (int r=0;r<4;r++){
      float m0 = fmaxf(fmaxf(s[mt][0][r], s[mt][1][r]), fmaxf(s[mt][2][r], s[mt][3][r]));
      #pragma unroll
      for (int o=8;o>=1;o>>=1) m0 = fmaxf(m0, __shfl_xor(m0,o));
      float sum = 0.f;
      float e[4];
      #pragma unroll
      for (int nt=0;nt<4;nt++){ e[nt] = __expf(s[mt][nt][r] - m0); sum += e[nt]; }
      #pragma unroll
      for (int o=8;o>=1;o>>=1) sum += __shfl_xor(sum,o);
      const float rinv = 1.f/sum;
      union { unsigned long long d; u16 u[4]; } pk;
      #pragma unroll
      for (int nt=0;nt<4;nt++) pk.u[nt] = f2b(e[nt]*rinv);
      *(unsigned long long*)(&P[(mt*16 + quad*4 + r)*72 + l16*4]) = pk.d;
    }
  }

  float4v o2[4][2];
  #pragma unroll
  for (int mt=0;mt<4;mt++){ o2[mt][0]=(float4v){0.f,0.f,0.f,0.f}; o2[mt][1]=(float4v){0.f,0.f,0.f,0.f}; }
  #pragma unroll
  for (int s2=0;s2<2;s2++){
    short8 vfrag[2];
    #pragma unroll
    for (int ct=0;ct<2;ct++) vfrag[ct] = *(const short8*)(&VT[(ct*16 + l16)*72 + s2*32 + quad*8]);
    #pragma unroll
    for (int mt=0;mt<4;mt++){
      short8 pfrag = *(const short8*)(&P[(mt*16 + l16)*72 + s2*32 + quad*8]);
      #pragma unroll
      for (int ct=0;ct<2;ct++)
        o2[mt][ct] = __builtin_amdgcn_mfma_f32_16x16x32_bf16(pfrag, vfrag[ct], o2[mt][ct], 0,0,0);
    }
  }

  #pragma unroll
  for (int mt=0;mt<4;mt++)
    #pragma unroll
    for (int ct=0;ct<2;ct++)
      #pragma unroll
      for (int r=0;r<4;r++){
        int i = mt*16 + quad*4 + r;
        out[((size_t)win*64 + i)*192 + hg*32 + ct*16 + l16] = f2b(o2[mt][ct][r]);
      }
}

// ---------------- driver ----------------
extern "C" void kernel_launch(void* const* d_in, const int* in_sizes, int n_in,
                              void* d_out, int out_size, void* d_ws, size_t ws_size,
                              hipStream_t stream)
{
  const float* x    = (const float*)d_in[0];
  const float* g1   = (const float*)d_in[1];
  const float* b1   = (const float*)d_in[2];
  const float* wqkv = (const float*)d_in[3];
  const float* bqkv = (const float*)d_in[4];
  const float* wo   = (const float*)d_in[5];
  const float* bo   = (const float*)d_in[6];
  const float* btab = (const float*)d_in[7];
  const float* g2   = (const float*)d_in[8];
  const float* b2v  = (const float*)d_in[9];
  const float* w1   = (const float*)d_in[10];
  const float* bm1  = (const float*)d_in[11];
  const float* w2   = (const float*)d_in[12];
  const float* bm2  = (const float*)d_in[13];
  float* out = (float*)d_out;

  char* ws = (char*)d_ws;
  u16*  wqkvT = (u16*)(ws + 0);            // [576][192]
  u16*  woT   = (u16*)(ws + 221184);       // [192][192]
  u16*  w1T   = (u16*)(ws + 294912);       // [768][192]
  u16*  w2T   = (u16*)(ws + 589824);       // [192][768]
  u16*  xw    = (u16*)(ws + 1048576);      // 65536x192 bf16
  u16*  qkvb  = (u16*)(ws + 26214400);     // 65536x576 bf16 (dead after attn)
  float* xo   = (float*)(ws + 26214400);   // 65536x192 fp32 (overlays dead qkv)
  u16*  xn2   = (u16*)(ws + 76546048);     // 65536x192 bf16
  int nslice; u16* h1s;
  if (ws_size >= (size_t)160000000){ nslice = 2; h1s = (u16*)(ws + 101711872); }
  else                              { nslice = 4; h1s = xw; }

  transpose_all<<<1728,256,0,stream>>>(wqkv, wo, w1, w2, wqkvT, woT, w1T, w2T);

  // LN1 + shift + window partition  (fp32 x -> bf16 xw)
  ln_kernel<true><<<16384,256,0,stream>>>(x, g1, b1, xw);
  // QKV projection (+ q-scale): [65536,192] @ [192,576]
  gemm_fk<4><<<dim3(9,1024),256,0,stream>>>(xw, wqkvT, bqkv, 192, 576, qkvb, nullptr, nullptr);
  // MFMA windowed attention (writes attn_out over xw)
  attn_mfma<<<2048,192,0,stream>>>(qkvb, btab, xw);
  // output projection + window-reverse + unshift + fp32 x residual -> xo (fp32)
  gemm_fk<2><<<dim3(3,1024),256,0,stream>>>(xw, woT, bo, 192, 192, nullptr, xo, x);
  // LN2 (fp32 xo -> bf16 xn2)
  ln_kernel<false><<<16384,256,0,stream>>>(xo, g2, b2v, xn2);
  // MLP in slices
  const int rows = 65536 / nslice;
  for (int sIdx = 0; sIdx < nslice; sIdx++){
    size_t ro = (size_t)sIdx * rows;
    gemm_fk<1><<<dim3(12,rows/64),256,0,stream>>>(xn2 + ro*192, w1T, bm1, 192, 768, h1s, nullptr, nullptr);
    gemm_fk<3><<<dim3(3,rows/64),256,0,stream>>>(h1s, w2T, bm2, 768, 192, nullptr, out + ro*192, xo + ro*192);
  }
}

// Round 6
// 370.204 us; speedup vs baseline: 1.3986x; 1.0174x over previous
//
#include <hip/hip_runtime.h>
#include <math.h>

typedef unsigned short u16;
typedef unsigned int   u32;
using short8  = __attribute__((ext_vector_type(8))) short;
using float4v = __attribute__((ext_vector_type(4))) float;

__device__ __forceinline__ float b2f(u16 u){ return __uint_as_float(((u32)u)<<16); }
__device__ __forceinline__ u16 f2b(float f){
  u32 x = __float_as_uint(f);
  x += 0x7FFFu + ((x>>16)&1u);   // RNE; inputs are tame (no NaN)
  return (u16)(x>>16);
}

// async global->LDS, 16B per lane. LDS dest = wave-uniform base + lane*16.
__device__ __forceinline__ void gload_lds16(const u16* g, u16* l){
  __builtin_amdgcn_global_load_lds((const __attribute__((address_space(1))) void*)g,
                                   (__attribute__((address_space(3))) void*)l, 16, 0, 0);
}

// ---------------- all 4 weight transposes (+fp32->bf16) in one launch ----------------
__global__ void transpose_all(const float* __restrict__ wqkv, const float* __restrict__ wo,
                              const float* __restrict__ w1,   const float* __restrict__ w2,
                              u16* __restrict__ wqkvT, u16* __restrict__ woT,
                              u16* __restrict__ w1T,   u16* __restrict__ w2T){
  int idx = blockIdx.x*256 + threadIdx.x;
  if (idx < 110592){ int r=idx/576, c=idx-r*576; wqkvT[c*192+r]=f2b(wqkv[idx]); }
  else if (idx < 147456){ int j=idx-110592; int r=j/192, c=j-r*192; woT[c*192+r]=f2b(wo[j]); }
  else if (idx < 294912){ int j=idx-147456; int r=j/768, c=j-r*768; w1T[c*192+r]=f2b(w1[j]); }
  else if (idx < 442368){ int j=idx-294912; int r=j/192, c=j-r*192; w2T[c*768+r]=f2b(w2[j]); }
}

// ---------------- LayerNorm (fp32 in, bf16 out); PART=true: roll(-2) + window partition ----------------
template<bool PART>
__global__ __launch_bounds__(256) void ln_kernel(const float* __restrict__ x,
    const float* __restrict__ g, const float* __restrict__ bvec,
    u16* __restrict__ out)
{
  int wave = threadIdx.x >> 6, lane = threadIdx.x & 63;
  int token = blockIdx.x*4 + wave;          // 0..65535
  int src, dst;
  if (PART){
    int b = token >> 15, r = token & 32767; // token enumerates SHIFTED coords
    int hs = r >> 10, ws = (r >> 5) & 31, ds = r & 31;
    int h = (hs+2)&31, w = (ws+2)&31, d = (ds+2)&31;   // sx[hs] = xn[(hs+2)%32]
    src = ((b*32 + h)*32 + w)*32 + d;
    int win = ((b*8 + (hs>>2))*8 + (ws>>2))*8 + (ds>>2);
    int n   = ((hs&3)*4 + (ws&3))*4 + (ds&3);
    dst = win*64 + n;
  } else { src = token; dst = token; }
  float v[3];
  #pragma unroll
  for (int t=0;t<3;t++) v[t] = x[(size_t)src*192 + lane + t*64];
  float s  = v[0]+v[1]+v[2];
  float s2 = v[0]*v[0]+v[1]*v[1]+v[2]*v[2];
  #pragma unroll
  for (int o=32;o>=1;o>>=1){ s += __shfl_xor(s,o); s2 += __shfl_xor(s2,o); }
  float mean = s*(1.0f/192.0f);
  float var  = s2*(1.0f/192.0f) - mean*mean;
  float rstd = rsqrtf(var + 1e-5f);
  #pragma unroll
  for (int t=0;t<3;t++){
    int c = lane + t*64;
    out[(size_t)dst*192 + c] = f2b((v[t]-mean)*rstd*g[c] + bvec[c]);
  }
}

// ---------------- MFMA GEMM, full-K-chunk, XCD-swizzled grid ----------------
// 1-D grid of 8*128*NB blocks: xcd = blk&7 owns contiguous m-range [xcd*128,+128) so A is
// fetched once per XCD L2. 64x64 block, 4 waves x 32x32 tiles, BK=192 single pass.
// MODE 2: bias + fp32 x residual, scatter window-reverse+roll(+2) -> outf (fp32 xo)
// MODE 4: bias -> outb, cols<192 scaled by hd^-0.5 (q-scale folded into QKV proj)
template<int MODE, int NB>
__global__ __launch_bounds__(256) void gemm_fk(
    const u16* __restrict__ A, const u16* __restrict__ BT, const float* __restrict__ bias,
    const int K, const int N,
    u16* __restrict__ outb, float* __restrict__ outf, const float* __restrict__ resf)
{
  __shared__ u16 As[64*192];   // 24 KB
  __shared__ u16 Bs[64*192];   // 24 KB
  const int lin = blockIdx.x;
  const int xcd = lin & 7, idx = lin >> 3;
  const int mb = idx / NB, nb = idx - mb*NB;
  const int m0 = (xcd*128 + mb) * 64, n0 = nb * 64;
  const int tid = threadIdx.x;
  const int wv = tid >> 6, lane = tid & 63;
  const int quad = lane >> 4, l16 = lane & 15;
  const int wm = (wv >> 1) * 32, wn = (wv & 1) * 32;   // wave's 32x32 tile

  float4v acc[2][2];
  #pragma unroll
  for (int a=0;a<2;a++) for (int b=0;b<2;b++) acc[a][b] = (float4v){0.f,0.f,0.f,0.f};

  const int srow8 = lane >> 3;             // row within octet
  const int scc   = (lane & 7) ^ srow8;    // swizzled source chunk within 128B group
  const int c3x   = l16 & 7;               // fragment-read swizzle phase

  for (int kc = 0; kc < K; kc += 192){
    #pragma unroll
    for (int t=0;t<6;t++){
      int ig = wv*6 + t;                   // 0..23 : (group g, row-octet ro)
      int g = ig >> 3, ro = ig & 7;
      int row = ro*8 + srow8;
      gload_lds16(A  + (size_t)(m0+row)*K + kc + g*64 + scc*8, As + g*4096 + ro*512);
      gload_lds16(BT + (size_t)(n0+row)*K + kc + g*64 + scc*8, Bs + g*4096 + ro*512);
    }
    __syncthreads();
    #pragma unroll
    for (int ks=0; ks<6; ks++){
      const int cc = ks*4 + quad, g = cc >> 3, c3 = (cc & 7) ^ c3x;
      short8 af[2], bf2[2];
      #pragma unroll
      for (int mt=0;mt<2;mt++) af[mt]  = *(const short8*)(As + g*4096 + (wm+mt*16+l16)*64 + c3*8);
      #pragma unroll
      for (int nt=0;nt<2;nt++) bf2[nt] = *(const short8*)(Bs + g*4096 + (wn+nt*16+l16)*64 + c3*8);
      #pragma unroll
      for (int mt=0;mt<2;mt++)
        #pragma unroll
        for (int nt=0;nt<2;nt++)
          acc[mt][nt] = __builtin_amdgcn_mfma_f32_16x16x32_bf16(af[mt], bf2[nt], acc[mt][nt], 0,0,0);
    }
    if (kc + 192 < K) __syncthreads();
  }

  #pragma unroll
  for (int nt=0;nt<2;nt++){
    int col = n0 + wn + nt*16 + l16;
    float bv = bias[col];
    #pragma unroll
    for (int mt=0;mt<2;mt++){
      float4v a = acc[mt][nt];
      #pragma unroll
      for (int r=0;r<4;r++){
        int mrow = m0 + wm + mt*16 + quad*4 + r;
        float v = a[r] + bv;
        if (MODE == 4){
          if (col < 192) v *= 0.17677669529663687f;
          outb[(size_t)mrow*N + col] = f2b(v);
        } else {
          int win = mrow >> 6, n = mrow & 63;
          int b = win >> 9, rw = win & 511;
          int hs = ((rw>>6)&7)*4 + (n>>4);
          int ws = ((rw>>3)&7)*4 + ((n>>2)&3);
          int ds = (rw&7)*4 + (n&3);
          int h=(hs+2)&31, w=(ws+2)&31, d=(ds+2)&31;       // roll(+2)
          size_t t = (size_t)((b*32+h)*32+w)*32 + d;
          outf[t*192 + col] = v + resf[t*192 + col];       // + original x (fp32)
        }
      }
    }
  }
}

// ---------------- fused MLP: out = xo + (gelu(xn2@w1+bm1))@w2 + bm2 ----------------
// 1 block = 64 tokens, 512 threads (8 waves). h (64x768 bf16) lives in LDS only.
// Weights read as direct 16B global fragments (L2-resident, no staging barriers).
// UP computes h^T tiles (D[m=hc][n=tok]) so each lane's 4 reg-values are 4 consecutive
// hc of ONE token -> single ds_write_b64. Hsh 16B-group XOR swizzle (g ^= tok&7):
// quarter-wave analysis => conflict-free for b64 writes and b128 B-frag reads.
// DOWN computes out^T (A=w2T[outcol][k], B=h[tok][k]); epilogue float4 fp32 store.
__global__ __launch_bounds__(512) void mlp_fused(
    const u16* __restrict__ xn2, const u16* __restrict__ w1T, const float* __restrict__ bm1,
    const u16* __restrict__ w2T, const float* __restrict__ bm2,
    const float* __restrict__ xo, float* __restrict__ out)
{
  __shared__ u16 Ash[64*192];   // 24 KB xn2 tile (gemm_fk swizzle)
  __shared__ u16 Hsh[64*768];   // 96 KB h, row-major + 16B-group XOR swizzle
  const int tid = threadIdx.x;
  const int wv = tid >> 6, lane = tid & 63;
  const int quad = lane >> 4, l16 = lane & 15;
  const int tok0 = blockIdx.x * 64;
  const int c3x = l16 & 7;

  // stage Ash: 24 DMA instrs, 3 per wave
  {
    const int srow8 = lane >> 3, scc = (lane & 7) ^ srow8;
    #pragma unroll
    for (int t=0;t<3;t++){
      int ig = wv*3 + t;
      int g = ig >> 3, ro = ig & 7;
      int row = ro*8 + srow8;
      gload_lds16(xn2 + (size_t)(tok0+row)*192 + g*64 + scc*8, Ash + g*4096 + ro*512);
    }
  }
  __syncthreads();

  // ---- UP: wave wv covers hc in [wv*96, wv*96+96), two passes of 3 m-tiles ----
  #pragma unroll
  for (int p=0;p<2;p++){
    float4v acc[3][4];
    #pragma unroll
    for (int a=0;a<3;a++) for (int b=0;b<4;b++) acc[a][b] = (float4v){0.f,0.f,0.f,0.f};
    const int mtb = wv*6 + p*3;
    #pragma unroll
    for (int ks=0; ks<6; ks++){
      const int cc = ks*4 + quad, g = cc >> 3, c3 = (cc & 7) ^ c3x;
      short8 bf[4], af[3];
      #pragma unroll
      for (int nt=0;nt<4;nt++) bf[nt] = *(const short8*)(Ash + g*4096 + (nt*16+l16)*64 + c3*8);
      #pragma unroll
      for (int mtl=0;mtl<3;mtl++){
        int hc = (mtb+mtl)*16 + l16;
        af[mtl] = *(const short8*)(w1T + (size_t)hc*192 + ks*32 + quad*8);
      }
      #pragma unroll
      for (int mtl=0;mtl<3;mtl++)
        #pragma unroll
        for (int nt=0;nt<4;nt++)
          acc[mtl][nt] = __builtin_amdgcn_mfma_f32_16x16x32_bf16(af[mtl], bf[nt], acc[mtl][nt], 0,0,0);
    }
    // epilogue: bias + exact GELU -> packed b64 into swizzled Hsh
    #pragma unroll
    for (int mtl=0;mtl<3;mtl++){
      const int hc0 = (mtb+mtl)*16 + quad*4;
      const float4v bv = *(const float4v*)(bm1 + hc0);
      const int g = hc0 >> 3, sub = hc0 & 7;     // sub in {0,4}
      #pragma unroll
      for (int nt=0;nt<4;nt++){
        const int tok = nt*16 + l16;
        union { unsigned long long d; u16 u[4]; } pk;
        #pragma unroll
        for (int r=0;r<4;r++){
          float v = acc[mtl][nt][r] + bv[r];
          v = 0.5f*v*(1.0f + erff(v*0.70710678118654752f));
          pk.u[r] = f2b(v);
        }
        *(unsigned long long*)(Hsh + tok*768 + ((g ^ (tok&7))<<3) + sub) = pk.d;
      }
    }
  }
  __syncthreads();

  // ---- DOWN: out^T tiles; wave: m-tiles (wv&3)*3+{0..2}, n-tiles (wv>>2)*2+{0,1} ----
  {
    const int mb = (wv&3)*3, nb = (wv>>2)*2;
    float4v acc[3][2];
    #pragma unroll
    for (int a=0;a<3;a++) for (int b=0;b<2;b++) acc[a][b] = (float4v){0.f,0.f,0.f,0.f};
    #pragma unroll 4
    for (int ks=0; ks<24; ks++){
      const int g = ks*4 + quad;
      short8 bf[2], af[3];
      #pragma unroll
      for (int ntl=0;ntl<2;ntl++){
        int tok = (nb+ntl)*16 + l16;
        bf[ntl] = *(const short8*)(Hsh + tok*768 + ((g ^ (tok&7))<<3));
      }
      #pragma unroll
      for (int mtl=0;mtl<3;mtl++){
        int oc = (mb+mtl)*16 + l16;
        af[mtl] = *(const short8*)(w2T + (size_t)oc*768 + ks*32 + quad*8);
      }
      #pragma unroll
      for (int mtl=0;mtl<3;mtl++)
        #pragma unroll
        for (int ntl=0;ntl<2;ntl++)
          acc[mtl][ntl] = __builtin_amdgcn_mfma_f32_16x16x32_bf16(af[mtl], bf[ntl], acc[mtl][ntl], 0,0,0);
    }
    #pragma unroll
    for (int mtl=0;mtl<3;mtl++){
      const int oc0 = (mb+mtl)*16 + quad*4;
      const float4v bv = *(const float4v*)(bm2 + oc0);
      #pragma unroll
      for (int ntl=0;ntl<2;ntl++){
        const int tok = tok0 + (nb+ntl)*16 + l16;
        const float4v res = *(const float4v*)(xo + (size_t)tok*192 + oc0);
        float4v o;
        #pragma unroll
        for (int r=0;r<4;r++) o[r] = acc[mtl][ntl][r] + bv[r] + res[r];
        *(float4v*)(out + (size_t)tok*192 + oc0) = o;
      }
    }
  }
}

// ---------------- MFMA windowed attention (unchanged) ----------------
__global__ __launch_bounds__(192,3) void attn_mfma(
    const u16* __restrict__ qkv, const float* __restrict__ bias_table,
    u16* __restrict__ out)
{
  __shared__ u16  Psh [3][64*72];
  __shared__ u16  VTsh[3][32*72];
  __shared__ float bsh[3][344];
  const int win  = blockIdx.x >> 1;
  const int wv   = threadIdx.x / 64;
  const int lane = threadIdx.x & 63;
  const int hg   = (blockIdx.x & 1)*3 + wv;
  const int quad = lane >> 4, l16 = lane & 15;

  u16* P  = &Psh[wv][0];
  u16* VT = &VTsh[wv][0];
  float* bs = &bsh[wv][0];
  const u16* base = qkv + (size_t)win*64*576 + hg*32;

  for (int idx = lane; idx < 343; idx += 64) bs[idx] = bias_table[idx*6 + hg];

  {
    const int a = (lane & 15)*4 + (lane >> 4);
    #pragma unroll
    for (int t=0;t<4;t++){
      union { uint4 v; u16 u[8]; } vv;
      vv.v = *(const uint4*)(base + (size_t)lane*576 + 384 + t*8);
      #pragma unroll
      for (int e=0;e<8;e++) VT[(t*8+e)*72 + a] = vv.u[e];
    }
  }

  short8 qf[4], kf[4];
  #pragma unroll
  for (int mt=0;mt<4;mt++) qf[mt] = *(const short8*)(base + (size_t)(mt*16 + l16)*576 + quad*8);
  #pragma unroll
  for (int nt=0;nt<4;nt++) kf[nt] = *(const short8*)(base + (size_t)(nt*16 + l16)*576 + 192 + quad*8);

  float4v s[4][4];
  #pragma unroll
  for (int mt=0;mt<4;mt++)
    #pragma unroll
    for (int nt=0;nt<4;nt++)
      s[mt][nt] = __builtin_amdgcn_mfma_f32_16x16x32_bf16(qf[mt], kf[nt], (float4v){0.f,0.f,0.f,0.f}, 0,0,0);

  const int rwn = win & 511;
  const int bh=(rwn>>6)&7, bw=(rwn>>3)&7, bd=rwn&7;
  const int jw = l16>>2, jd = l16&3;
  const int gw_j = (bw==7) ? ((jw  <2)?3:6) : 0;
  const int gd_j = (bd==7) ? ((jd  <2)?1:2) : 0;
  const int gw_i = (bw==7) ? ((quad<2)?3:6) : 0;
  const int laneoff = (quad - jw)*7 - jd + 171;
  #pragma unroll
  for (int mt=0;mt<4;mt++){
    const int gh_i = (bh==7) ? ((mt<2)?9:18) : 0;
    #pragma unroll
    for (int nt=0;nt<4;nt++){
      const int gh_j = (bh==7) ? ((nt<2)?9:18) : 0;
      const int bb = (mt-nt)*49 + laneoff;
      #pragma unroll
      for (int r=0;r<4;r++){
        const int gd_i = (bd==7) ? ((r<2)?1:2) : 0;
        float sv = s[mt][nt][r] + bs[bb + r];
        if ((gh_i + gw_i + gd_i) != (gh_j + gw_j + gd_j)) sv -= 100.f;
        s[mt][nt][r] = sv;
      }
    }
  }

  #pragma unroll
  for (int mt=0;mt<4;mt++){
    #pragma unroll
    for (int r=0;r<4;r++){
      float m0 = fmaxf(fmaxf(s[mt][0][r], s[mt][1][r]), fmaxf(s[mt][2][r], s[mt][3][r]));
      #pragma unroll
      for (int o=8;o>=1;o>>=1) m0 = fmaxf(m0, __shfl_xor(m0,o));
      float sum = 0.f;
      float e[4];
      #pragma unroll
      for (int nt=0;nt<4;nt++){ e[nt] = __expf(s[mt][nt][r] - m0); sum += e[nt]; }
      #pragma unroll
      for (int o=8;o>=1;o>>=1) sum += __shfl_xor(sum,o);
      const float rinv = 1.f/sum;
      union { unsigned long long d; u16 u[4]; } pk;
      #pragma unroll
      for (int nt=0;nt<4;nt++) pk.u[nt] = f2b(e[nt]*rinv);
      *(unsigned long long*)(&P[(mt*16 + quad*4 + r)*72 + l16*4]) = pk.d;
    }
  }

  float4v o2[4][2];
  #pragma unroll
  for (int mt=0;mt<4;mt++){ o2[mt][0]=(float4v){0.f,0.f,0.f,0.f}; o2[mt][1]=(float4v){0.f,0.f,0.f,0.f}; }
  #pragma unroll
  for (int s2=0;s2<2;s2++){
    short8 vfrag[2];
    #pragma unroll
    for (int ct=0;ct<2;ct++) vfrag[ct] = *(const short8*)(&VT[(ct*16 + l16)*72 + s2*32 + quad*8]);
    #pragma unroll
    for (int mt=0;mt<4;mt++){
      short8 pfrag = *(const short8*)(&P[(mt*16 + l16)*72 + s2*32 + quad*8]);
      #pragma unroll
      for (int ct=0;ct<2;ct++)
        o2[mt][ct] = __builtin_amdgcn_mfma_f32_16x16x32_bf16(pfrag, vfrag[ct], o2[mt][ct], 0,0,0);
    }
  }

  #pragma unroll
  for (int mt=0;mt<4;mt++)
    #pragma unroll
    for (int ct=0;ct<2;ct++)
      #pragma unroll
      for (int r=0;r<4;r++){
        int i = mt*16 + quad*4 + r;
        out[((size_t)win*64 + i)*192 + hg*32 + ct*16 + l16] = f2b(o2[mt][ct][r]);
      }
}

// ---------------- driver ----------------
extern "C" void kernel_launch(void* const* d_in, const int* in_sizes, int n_in,
                              void* d_out, int out_size, void* d_ws, size_t ws_size,
                              hipStream_t stream)
{
  const float* x    = (const float*)d_in[0];
  const float* g1   = (const float*)d_in[1];
  const float* b1   = (const float*)d_in[2];
  const float* wqkv = (const float*)d_in[3];
  const float* bqkv = (const float*)d_in[4];
  const float* wo   = (const float*)d_in[5];
  const float* bo   = (const float*)d_in[6];
  const float* btab = (const float*)d_in[7];
  const float* g2   = (const float*)d_in[8];
  const float* b2v  = (const float*)d_in[9];
  const float* w1   = (const float*)d_in[10];
  const float* bm1  = (const float*)d_in[11];
  const float* w2   = (const float*)d_in[12];
  const float* bm2  = (const float*)d_in[13];
  float* out = (float*)d_out;

  char* ws = (char*)d_ws;
  u16*  wqkvT = (u16*)(ws + 0);            // [576][192]
  u16*  woT   = (u16*)(ws + 221184);       // [192][192]
  u16*  w1T   = (u16*)(ws + 294912);       // [768][192]
  u16*  w2T   = (u16*)(ws + 589824);       // [192][768]
  u16*  xw    = (u16*)(ws + 1048576);      // 65536x192 bf16
  u16*  qkvb  = (u16*)(ws + 26214400);     // 65536x576 bf16 (dead after attn)
  float* xo   = (float*)(ws + 26214400);   // 65536x192 fp32 (overlays dead qkv)
  u16*  xn2   = (u16*)(ws + 76546048);     // 65536x192 bf16

  transpose_all<<<1728,256,0,stream>>>(wqkv, wo, w1, w2, wqkvT, woT, w1T, w2T);

  // LN1 + shift + window partition  (fp32 x -> bf16 xw)
  ln_kernel<true><<<16384,256,0,stream>>>(x, g1, b1, xw);
  // QKV projection (+ q-scale): [65536,192] @ [192,576], XCD-swizzled
  gemm_fk<4,9><<<9216,256,0,stream>>>(xw, wqkvT, bqkv, 192, 576, qkvb, nullptr, nullptr);
  // MFMA windowed attention (writes attn_out over xw)
  attn_mfma<<<2048,192,0,stream>>>(qkvb, btab, xw);
  // output projection + window-reverse + unshift + fp32 x residual -> xo (fp32)
  gemm_fk<2,3><<<3072,256,0,stream>>>(xw, woT, bo, 192, 192, nullptr, xo, x);
  // LN2 (fp32 xo -> bf16 xn2)
  ln_kernel<false><<<16384,256,0,stream>>>(xo, g2, b2v, xn2);
  // fused MLP: out = xo + gelu(xn2@w1+bm1)@w2 + bm2
  mlp_fused<<<1024,512,0,stream>>>(xn2, w1T, bm1, w2T, bm2, xo, out);
}

// Round 7
// 350.429 us; speedup vs baseline: 1.4776x; 1.0564x over previous
//
#include <hip/hip_runtime.h>
#include <math.h>

typedef unsigned short u16;
typedef unsigned int   u32;
using short8  = __attribute__((ext_vector_type(8))) short;
using float4v = __attribute__((ext_vector_type(4))) float;

__device__ __forceinline__ float b2f(u16 u){ return __uint_as_float(((u32)u)<<16); }
__device__ __forceinline__ u16 f2b(float f){
  u32 x = __float_as_uint(f);
  x += 0x7FFFu + ((x>>16)&1u);   // RNE; inputs are tame (no NaN)
  return (u16)(x>>16);
}

// async global->LDS, 16B per lane. LDS dest = wave-uniform base + lane*16.
__device__ __forceinline__ void gload_lds16(const u16* g, u16* l){
  __builtin_amdgcn_global_load_lds((const __attribute__((address_space(1))) void*)g,
                                   (__attribute__((address_space(3))) void*)l, 16, 0, 0);
}

// tanh-form GELU: |err vs exact erf-GELU| <~3e-3, invisible under bf16 h + 0.08 margin
__device__ __forceinline__ float gelu_t(float x){
  float u = 1.5957691216f*(x + 0.044715f*x*x*x);      // 2*0.7978845608
  float t = 1.f - 2.f/(1.f + __expf(u));              // tanh(u/2*2)=tanh(0.797..*(..))
  return 0.5f*x*(1.f + t);
}

// ---------------- all 4 weight transposes (+fp32->bf16) in one launch ----------------
__global__ void transpose_all(const float* __restrict__ wqkv, const float* __restrict__ wo,
                              const float* __restrict__ w1,   const float* __restrict__ w2,
                              u16* __restrict__ wqkvT, u16* __restrict__ woT,
                              u16* __restrict__ w1T,   u16* __restrict__ w2T){
  int idx = blockIdx.x*256 + threadIdx.x;
  if (idx < 110592){ int r=idx/576, c=idx-r*576; wqkvT[c*192+r]=f2b(wqkv[idx]); }
  else if (idx < 147456){ int j=idx-110592; int r=j/192, c=j-r*192; woT[c*192+r]=f2b(wo[j]); }
  else if (idx < 294912){ int j=idx-147456; int r=j/768, c=j-r*768; w1T[c*192+r]=f2b(w1[j]); }
  else if (idx < 442368){ int j=idx-294912; int r=j/192, c=j-r*192; w2T[c*768+r]=f2b(w2[j]); }
}

// ---------------- LayerNorm1 (fp32 in, bf16 out) + roll(-2) + window partition ----------------
__global__ __launch_bounds__(256) void ln_kernel(const float* __restrict__ x,
    const float* __restrict__ g, const float* __restrict__ bvec,
    u16* __restrict__ out)
{
  int wave = threadIdx.x >> 6, lane = threadIdx.x & 63;
  int token = blockIdx.x*4 + wave;          // enumerates SHIFTED coords
  int b = token >> 15, r = token & 32767;
  int hs = r >> 10, ws = (r >> 5) & 31, ds = r & 31;
  int h = (hs+2)&31, w = (ws+2)&31, d = (ds+2)&31;   // sx[hs] = xn[(hs+2)%32]
  int src = ((b*32 + h)*32 + w)*32 + d;
  int win = ((b*8 + (hs>>2))*8 + (ws>>2))*8 + (ds>>2);
  int n   = ((hs&3)*4 + (ws&3))*4 + (ds&3);
  int dst = win*64 + n;
  float v[3];
  #pragma unroll
  for (int t=0;t<3;t++) v[t] = x[(size_t)src*192 + lane + t*64];
  float s  = v[0]+v[1]+v[2];
  float s2 = v[0]*v[0]+v[1]*v[1]+v[2]*v[2];
  #pragma unroll
  for (int o=32;o>=1;o>>=1){ s += __shfl_xor(s,o); s2 += __shfl_xor(s2,o); }
  float mean = s*(1.0f/192.0f);
  float var  = s2*(1.0f/192.0f) - mean*mean;
  float rstd = rsqrtf(var + 1e-5f);
  #pragma unroll
  for (int t=0;t<3;t++){
    int c = lane + t*64;
    out[(size_t)dst*192 + c] = f2b((v[t]-mean)*rstd*g[c] + bvec[c]);
  }
}

// ---------------- MFMA GEMM, full-K-chunk, XCD-swizzled grid ----------------
// MODE 2: bias + fp32 x residual, scatter window-reverse+roll(+2) -> outf (fp32 xo)
// MODE 4: bias -> outb, cols<192 scaled by hd^-0.5 (q-scale folded into QKV proj)
template<int MODE, int NB>
__global__ __launch_bounds__(256) void gemm_fk(
    const u16* __restrict__ A, const u16* __restrict__ BT, const float* __restrict__ bias,
    const int K, const int N,
    u16* __restrict__ outb, float* __restrict__ outf, const float* __restrict__ resf)
{
  __shared__ u16 As[64*192];   // 24 KB
  __shared__ u16 Bs[64*192];   // 24 KB
  const int lin = blockIdx.x;
  const int xcd = lin & 7, idx = lin >> 3;
  const int mb = idx / NB, nb = idx - mb*NB;
  const int m0 = (xcd*128 + mb) * 64, n0 = nb * 64;
  const int tid = threadIdx.x;
  const int wv = tid >> 6, lane = tid & 63;
  const int quad = lane >> 4, l16 = lane & 15;
  const int wm = (wv >> 1) * 32, wn = (wv & 1) * 32;   // wave's 32x32 tile

  float4v acc[2][2];
  #pragma unroll
  for (int a=0;a<2;a++) for (int b=0;b<2;b++) acc[a][b] = (float4v){0.f,0.f,0.f,0.f};

  const int srow8 = lane >> 3;             // row within octet
  const int scc   = (lane & 7) ^ srow8;    // swizzled source chunk within 128B group
  const int c3x   = l16 & 7;               // fragment-read swizzle phase

  for (int kc = 0; kc < K; kc += 192){
    #pragma unroll
    for (int t=0;t<6;t++){
      int ig = wv*6 + t;                   // 0..23 : (group g, row-octet ro)
      int g = ig >> 3, ro = ig & 7;
      int row = ro*8 + srow8;
      gload_lds16(A  + (size_t)(m0+row)*K + kc + g*64 + scc*8, As + g*4096 + ro*512);
      gload_lds16(BT + (size_t)(n0+row)*K + kc + g*64 + scc*8, Bs + g*4096 + ro*512);
    }
    __syncthreads();
    #pragma unroll
    for (int ks=0; ks<6; ks++){
      const int cc = ks*4 + quad, g = cc >> 3, c3 = (cc & 7) ^ c3x;
      short8 af[2], bf2[2];
      #pragma unroll
      for (int mt=0;mt<2;mt++) af[mt]  = *(const short8*)(As + g*4096 + (wm+mt*16+l16)*64 + c3*8);
      #pragma unroll
      for (int nt=0;nt<2;nt++) bf2[nt] = *(const short8*)(Bs + g*4096 + (wn+nt*16+l16)*64 + c3*8);
      #pragma unroll
      for (int mt=0;mt<2;mt++)
        #pragma unroll
        for (int nt=0;nt<2;nt++)
          acc[mt][nt] = __builtin_amdgcn_mfma_f32_16x16x32_bf16(af[mt], bf2[nt], acc[mt][nt], 0,0,0);
    }
    if (kc + 192 < K) __syncthreads();
  }

  #pragma unroll
  for (int nt=0;nt<2;nt++){
    int col = n0 + wn + nt*16 + l16;
    float bv = bias[col];
    #pragma unroll
    for (int mt=0;mt<2;mt++){
      float4v a = acc[mt][nt];
      #pragma unroll
      for (int r=0;r<4;r++){
        int mrow = m0 + wm + mt*16 + quad*4 + r;
        float v = a[r] + bv;
        if (MODE == 4){
          if (col < 192) v *= 0.17677669529663687f;
          outb[(size_t)mrow*N + col] = f2b(v);
        } else {
          int win = mrow >> 6, n = mrow & 63;
          int b = win >> 9, rw = win & 511;
          int hs = ((rw>>6)&7)*4 + (n>>4);
          int ws = ((rw>>3)&7)*4 + ((n>>2)&3);
          int ds = (rw&7)*4 + (n&3);
          int h=(hs+2)&31, w=(ws+2)&31, d=(ds+2)&31;       // roll(+2)
          size_t t = (size_t)((b*32+h)*32+w)*32 + d;
          outf[t*192 + col] = v + resf[t*192 + col];       // + original x (fp32)
        }
      }
    }
  }
}

// ---------------- fused LN2 + MLP: out = xo + gelu(ln(xo)@w1+bm1)@w2 + bm2 ----------------
// 1 block = 64 tokens, 512 threads. LDS = Ash 24 KB + Hsh 48 KB = 72 KB -> 2 blocks/CU
// (the round-6 96 KB Hsh forced 1 block/CU = the latency wall). Hidden dim processed in
// 2 halves of 384; DOWN accumulates across halves in 24 persistent VGPRs.
// LN2 is computed in-block (wave = 8 tokens) straight into the swizzled Ash.
__global__ __launch_bounds__(512,4) void mlp_fused(
    const float* __restrict__ xo, const float* __restrict__ g2, const float* __restrict__ b2,
    const u16* __restrict__ w1T, const float* __restrict__ bm1,
    const u16* __restrict__ w2T, const float* __restrict__ bm2,
    float* __restrict__ out)
{
  __shared__ u16 Ash[64*192];   // 24 KB  ln(xo) tile, gemm_fk swizzle
  __shared__ u16 Hsh[64*384];   // 48 KB  h half, row-major + 16B-group XOR swizzle
  const int tid = threadIdx.x;
  const int wv = tid >> 6, lane = tid & 63;
  const int quad = lane >> 4, l16 = lane & 15;
  const int tok0 = blockIdx.x * 64;
  const int c3x = l16 & 7;

  // ---- LN2 in-block: wave wv handles tokens wv*8..wv*8+7 ----
  {
    float gg[3], bb[3];
    #pragma unroll
    for (int t=0;t<3;t++){ gg[t] = g2[lane+t*64]; bb[t] = b2[lane+t*64]; }
    #pragma unroll
    for (int tt=0;tt<8;tt++){
      const int tl = wv*8 + tt;
      const float* row = xo + (size_t)(tok0+tl)*192;
      float v[3];
      #pragma unroll
      for (int t=0;t<3;t++) v[t] = row[lane + t*64];
      float s = v[0]+v[1]+v[2];
      float s2 = v[0]*v[0]+v[1]*v[1]+v[2]*v[2];
      #pragma unroll
      for (int o=32;o>=1;o>>=1){ s += __shfl_xor(s,o); s2 += __shfl_xor(s2,o); }
      float mean = s*(1.0f/192.0f);
      float rstd = rsqrtf(s2*(1.0f/192.0f) - mean*mean + 1e-5f);
      const int slot = ((lane>>3) ^ (tl&7));
      #pragma unroll
      for (int t=0;t<3;t++)
        Ash[t*4096 + tl*64 + slot*8 + (lane&7)] = f2b((v[t]-mean)*rstd*gg[t] + bb[t]);
    }
  }
  __syncthreads();

  // DOWN accumulators persist across both hidden halves
  const int mb = (wv&3)*3, nb = (wv>>2)*2;   // oc tiles, tok tiles
  float4v dacc[3][2];
  #pragma unroll
  for (int a=0;a<3;a++) for (int b=0;b<2;b++) dacc[a][b] = (float4v){0.f,0.f,0.f,0.f};

  #pragma unroll
  for (int half=0; half<2; half++){
    // ---- UP: wave covers 48 hidden cols of this half; h^T tiles (m=hc, n=tok) ----
    float4v acc[3][4];
    #pragma unroll
    for (int a=0;a<3;a++) for (int b=0;b<4;b++) acc[a][b] = (float4v){0.f,0.f,0.f,0.f};
    #pragma unroll
    for (int ks=0; ks<6; ks++){
      const int cc = ks*4 + quad, g = cc >> 3, c3 = (cc & 7) ^ c3x;
      short8 bf[4], af[3];
      #pragma unroll
      for (int nt=0;nt<4;nt++) bf[nt] = *(const short8*)(Ash + g*4096 + (nt*16+l16)*64 + c3*8);
      #pragma unroll
      for (int mtl=0;mtl<3;mtl++){
        int hc = half*384 + wv*48 + mtl*16 + l16;
        af[mtl] = *(const short8*)(w1T + (size_t)hc*192 + ks*32 + quad*8);
      }
      #pragma unroll
      for (int mtl=0;mtl<3;mtl++)
        #pragma unroll
        for (int nt=0;nt<4;nt++)
          acc[mtl][nt] = __builtin_amdgcn_mfma_f32_16x16x32_bf16(af[mtl], bf[nt], acc[mtl][nt], 0,0,0);
    }
    // bias + GELU -> packed b64 into swizzled Hsh (row stride 384)
    #pragma unroll
    for (int mtl=0;mtl<3;mtl++){
      const int hl0 = wv*48 + mtl*16 + quad*4;          // local hc within half
      const float4v bv = *(const float4v*)(bm1 + half*384 + hl0);
      const int g = hl0 >> 3, sub = hl0 & 7;            // sub in {0,4}
      #pragma unroll
      for (int nt=0;nt<4;nt++){
        const int tok = nt*16 + l16;
        union { unsigned long long d; u16 u[4]; } pk;
        #pragma unroll
        for (int r=0;r<4;r++) pk.u[r] = f2b(gelu_t(acc[mtl][nt][r] + bv[r]));
        *(unsigned long long*)(Hsh + tok*384 + ((g ^ (tok&7))<<3) + sub) = pk.d;
      }
    }
    __syncthreads();

    // ---- DOWN: accumulate out^T partial products for this half ----
    #pragma unroll 4
    for (int ks=0; ks<12; ks++){
      const int g = ks*4 + quad;
      short8 bf[2], af[3];
      #pragma unroll
      for (int ntl=0;ntl<2;ntl++){
        int tok = (nb+ntl)*16 + l16;
        bf[ntl] = *(const short8*)(Hsh + tok*384 + ((g ^ (tok&7))<<3));
      }
      #pragma unroll
      for (int mtl=0;mtl<3;mtl++){
        int oc = (mb+mtl)*16 + l16;
        af[mtl] = *(const short8*)(w2T + (size_t)oc*768 + half*384 + ks*32 + quad*8);
      }
      #pragma unroll
      for (int mtl=0;mtl<3;mtl++)
        #pragma unroll
        for (int ntl=0;ntl<2;ntl++)
          dacc[mtl][ntl] = __builtin_amdgcn_mfma_f32_16x16x32_bf16(af[mtl], bf[ntl], dacc[mtl][ntl], 0,0,0);
    }
    if (half == 0) __syncthreads();   // before UP half1 overwrites Hsh
  }

  // ---- epilogue: bias + xo residual, fp32 float4 stores ----
  #pragma unroll
  for (int mtl=0;mtl<3;mtl++){
    const int oc0 = (mb+mtl)*16 + quad*4;
    const float4v bv = *(const float4v*)(bm2 + oc0);
    #pragma unroll
    for (int ntl=0;ntl<2;ntl++){
      const int tok = tok0 + (nb+ntl)*16 + l16;
      const float4v res = *(const float4v*)(xo + (size_t)tok*192 + oc0);
      float4v o;
      #pragma unroll
      for (int r=0;r<4;r++) o[r] = dacc[mtl][ntl][r] + bv[r] + res[r];
      *(float4v*)(out + (size_t)tok*192 + oc0) = o;
    }
  }
}

// ---------------- MFMA windowed attention (unchanged) ----------------
__global__ __launch_bounds__(192,3) void attn_mfma(
    const u16* __restrict__ qkv, const float* __restrict__ bias_table,
    u16* __restrict__ out)
{
  __shared__ u16  Psh [3][64*72];
  __shared__ u16  VTsh[3][32*72];
  __shared__ float bsh[3][344];
  const int win  = blockIdx.x >> 1;
  const int wv   = threadIdx.x / 64;
  const int lane = threadIdx.x & 63;
  const int hg   = (blockIdx.x & 1)*3 + wv;
  const int quad = lane >> 4, l16 = lane & 15;

  u16* P  = &Psh[wv][0];
  u16* VT = &VTsh[wv][0];
  float* bs = &bsh[wv][0];
  const u16* base = qkv + (size_t)win*64*576 + hg*32;

  for (int idx = lane; idx < 343; idx += 64) bs[idx] = bias_table[idx*6 + hg];

  {
    const int a = (lane & 15)*4 + (lane >> 4);
    #pragma unroll
    for (int t=0;t<4;t++){
      union { uint4 v; u16 u[8]; } vv;
      vv.v = *(const uint4*)(base + (size_t)lane*576 + 384 + t*8);
      #pragma unroll
      for (int e=0;e<8;e++) VT[(t*8+e)*72 + a] = vv.u[e];
    }
  }

  short8 qf[4], kf[4];
  #pragma unroll
  for (int mt=0;mt<4;mt++) qf[mt] = *(const short8*)(base + (size_t)(mt*16 + l16)*576 + quad*8);
  #pragma unroll
  for (int nt=0;nt<4;nt++) kf[nt] = *(const short8*)(base + (size_t)(nt*16 + l16)*576 + 192 + quad*8);

  float4v s[4][4];
  #pragma unroll
  for (int mt=0;mt<4;mt++)
    #pragma unroll
    for (int nt=0;nt<4;nt++)
      s[mt][nt] = __builtin_amdgcn_mfma_f32_16x16x32_bf16(qf[mt], kf[nt], (float4v){0.f,0.f,0.f,0.f}, 0,0,0);

  const int rwn = win & 511;
  const int bh=(rwn>>6)&7, bw=(rwn>>3)&7, bd=rwn&7;
  const int jw = l16>>2, jd = l16&3;
  const int gw_j = (bw==7) ? ((jw  <2)?3:6) : 0;
  const int gd_j = (bd==7) ? ((jd  <2)?1:2) : 0;
  const int gw_i = (bw==7) ? ((quad<2)?3:6) : 0;
  const int laneoff = (quad - jw)*7 - jd + 171;
  #pragma unroll
  for (int mt=0;mt<4;mt++){
    const int gh_i = (bh==7) ? ((mt<2)?9:18) : 0;
    #pragma unroll
    for (int nt=0;nt<4;nt++){
      const int gh_j = (bh==7) ? ((nt<2)?9:18) : 0;
      const int bb = (mt-nt)*49 + laneoff;
      #pragma unroll
      for (int r=0;r<4;r++){
        const int gd_i = (bd==7) ? ((r<2)?1:2) : 0;
        float sv = s[mt][nt][r] + bs[bb + r];
        if ((gh_i + gw_i + gd_i) != (gh_j + gw_j + gd_j)) sv -= 100.f;
        s[mt][nt][r] = sv;
      }
    }
  }

  #pragma unroll
  for (int mt=0;mt<4;mt++){
    #pragma unroll
    for (int r=0;r<4;r++){
      float m0 = fmaxf(fmaxf(s[mt][0][r], s[mt][1][r]), fmaxf(s[mt][2][r], s[mt][3][r]));
      #pragma unroll
      for (int o=8;o>=1;o>>=1) m0 = fmaxf(m0, __shfl_xor(m0,o));
      float sum = 0.f;
      float e[4];
      #pragma unroll
      for (int nt=0;nt<4;nt++){ e[nt] = __expf(s[mt][nt][r] - m0); sum += e[nt]; }
      #pragma unroll
      for (int o=8;o>=1;o>>=1) sum += __shfl_xor(sum,o);
      const float rinv = 1.f/sum;
      union { unsigned long long d; u16 u[4]; } pk;
      #pragma unroll
      for (int nt=0;nt<4;nt++) pk.u[nt] = f2b(e[nt]*rinv);
      *(unsigned long long*)(&P[(mt*16 + quad*4 + r)*72 + l16*4]) = pk.d;
    }
  }

  float4v o2[4][2];
  #pragma unroll
  for (int mt=0;mt<4;mt++){ o2[mt][0]=(float4v){0.f,0.f,0.f,0.f}; o2[mt][1]=(float4v){0.f,0.f,0.f,0.f}; }
  #pragma unroll
  for (int s2=0;s2<2;s2++){
    short8 vfrag[2];
    #pragma unroll
    for (int ct=0;ct<2;ct++) vfrag[ct] = *(const short8*)(&VT[(ct*16 + l16)*72 + s2*32 + quad*8]);
    #pragma unroll
    for (int mt=0;mt<4;mt++){
      short8 pfrag = *(const short8*)(&P[(mt*16 + l16)*72 + s2*32 + quad*8]);
      #pragma unroll
      for (int ct=0;ct<2;ct++)
        o2[mt][ct] = __builtin_amdgcn_mfma_f32_16x16x32_bf16(pfrag, vfrag[ct], o2[mt][ct], 0,0,0);
    }
  }

  #pragma unroll
  for (int mt=0;mt<4;mt++)
    #pragma unroll
    for (int ct=0;ct<2;ct++)
      #pragma unroll
      for (int r=0;r<4;r++){
        int i = mt*16 + quad*4 + r;
        out[((size_t)win*64 + i)*192 + hg*32 + ct*16 + l16] = f2b(o2[mt][ct][r]);
      }
}

// ---------------- driver ----------------
extern "C" void kernel_launch(void* const* d_in, const int* in_sizes, int n_in,
                              void* d_out, int out_size, void* d_ws, size_t ws_size,
                              hipStream_t stream)
{
  const float* x    = (const float*)d_in[0];
  const float* g1   = (const float*)d_in[1];
  const float* b1   = (const float*)d_in[2];
  const float* wqkv = (const float*)d_in[3];
  const float* bqkv = (const float*)d_in[4];
  const float* wo   = (const float*)d_in[5];
  const float* bo   = (const float*)d_in[6];
  const float* btab = (const float*)d_in[7];
  const float* g2   = (const float*)d_in[8];
  const float* b2v  = (const float*)d_in[9];
  const float* w1   = (const float*)d_in[10];
  const float* bm1  = (const float*)d_in[11];
  const float* w2   = (const float*)d_in[12];
  const float* bm2  = (const float*)d_in[13];
  float* out = (float*)d_out;

  char* ws = (char*)d_ws;
  u16*  wqkvT = (u16*)(ws + 0);            // [576][192]
  u16*  woT   = (u16*)(ws + 221184);       // [192][192]
  u16*  w1T   = (u16*)(ws + 294912);       // [768][192]
  u16*  w2T   = (u16*)(ws + 589824);       // [192][768]
  u16*  xw    = (u16*)(ws + 1048576);      // 65536x192 bf16
  u16*  qkvb  = (u16*)(ws + 26214400);     // 65536x576 bf16 (dead after attn)
  float* xo   = (float*)(ws + 26214400);   // 65536x192 fp32 (overlays dead qkv)

  transpose_all<<<1728,256,0,stream>>>(wqkv, wo, w1, w2, wqkvT, woT, w1T, w2T);

  // LN1 + shift + window partition  (fp32 x -> bf16 xw)
  ln_kernel<<<16384,256,0,stream>>>(x, g1, b1, xw);
  // QKV projection (+ q-scale): [65536,192] @ [192,576], XCD-swizzled
  gemm_fk<4,9><<<9216,256,0,stream>>>(xw, wqkvT, bqkv, 192, 576, qkvb, nullptr, nullptr);
  // MFMA windowed attention (writes attn_out over xw)
  attn_mfma<<<2048,192,0,stream>>>(qkvb, btab, xw);
  // output projection + window-reverse + unshift + fp32 x residual -> xo (fp32)
  gemm_fk<2,3><<<3072,256,0,stream>>>(xw, woT, bo, 192, 192, nullptr, xo, x);
  // fused LN2 + MLP: out = xo + gelu(ln(xo)@w1+bm1)@w2 + bm2
  mlp_fused<<<1024,512,0,stream>>>(xo, g2, b2v, w1T, bm1, w2T, bm2, out);
}

// Round 8
// 315.608 us; speedup vs baseline: 1.6406x; 1.1103x over previous
//
#include <hip/hip_runtime.h>
#include <math.h>

typedef unsigned short u16;
typedef unsigned int   u32;
using short8  = __attribute__((ext_vector_type(8))) short;
using float4v = __attribute__((ext_vector_type(4))) float;

__device__ __forceinline__ float b2f(u16 u){ return __uint_as_float(((u32)u)<<16); }
__device__ __forceinline__ u16 f2b(float f){
  u32 x = __float_as_uint(f);
  x += 0x7FFFu + ((x>>16)&1u);   // RNE; inputs are tame (no NaN)
  return (u16)(x>>16);
}

// async global->LDS, 16B per lane. LDS dest = wave-uniform base + lane*16.
__device__ __forceinline__ void gload_lds16(const u16* g, u16* l){
  __builtin_amdgcn_global_load_lds((const __attribute__((address_space(1))) void*)g,
                                   (__attribute__((address_space(3))) void*)l, 16, 0, 0);
}

// tanh-form GELU: |err vs exact erf-GELU| <~3e-3, invisible under bf16 h + 0.08 margin
__device__ __forceinline__ float gelu_t(float x){
  float u = 1.5957691216f*(x + 0.044715f*x*x*x);
  float t = 1.f - 2.f/(1.f + __expf(u));
  return 0.5f*x*(1.f + t);
}

// ------- weight prep: wqkvT/woT transposed; w1P/w2P packed in MFMA A-fragment order -------
// w1P[hct(48)][ks(6)][quad][l16][e8]  <- w1[k=ks*32+quad*8+e][hc=hct*16+l16]   (coalesced af loads)
// w2P[oct(12)][kk(24)][quad][l16][e8] <- w2[k=kk*32+quad*8+e][oc=oct*16+l16]
__global__ void transpose_all(const float* __restrict__ wqkv, const float* __restrict__ wo,
                              const float* __restrict__ w1,   const float* __restrict__ w2,
                              u16* __restrict__ wqkvT, u16* __restrict__ woT,
                              u16* __restrict__ w1P,   u16* __restrict__ w2P){
  int idx = blockIdx.x*256 + threadIdx.x;
  if (idx < 110592){ int r=idx/576, c=idx-r*576; wqkvT[c*192+r]=f2b(wqkv[idx]); }
  else if (idx < 147456){ int j=idx-110592; int r=j/192, c=j-r*192; woT[c*192+r]=f2b(wo[j]); }
  else if (idx < 294912){
    int j = idx-147456;
    int tile = j >> 9, w = j & 511;            // tile = hct*6+ks
    int e = w & 7, l16 = (w>>3)&15, quad = w>>7;
    int hc = (tile/6)*16 + l16, k = (tile%6)*32 + quad*8 + e;
    w1P[j] = f2b(w1[k*768 + hc]);
  } else if (idx < 442368){
    int j = idx-294912;
    int tile = j >> 9, w = j & 511;            // tile = oct*24+kk
    int e = w & 7, l16 = (w>>3)&15, quad = w>>7;
    int oc = (tile/24)*16 + l16, k = (tile%24)*32 + quad*8 + e;
    w2P[j] = f2b(w2[k*192 + oc]);
  }
}

// ---------------- LayerNorm1 (fp32 in, bf16 out) + roll(-2) + window partition ----------------
__global__ __launch_bounds__(256) void ln_kernel(const float* __restrict__ x,
    const float* __restrict__ g, const float* __restrict__ bvec,
    u16* __restrict__ out)
{
  int wave = threadIdx.x >> 6, lane = threadIdx.x & 63;
  int token = blockIdx.x*4 + wave;          // enumerates SHIFTED coords
  int b = token >> 15, r = token & 32767;
  int hs = r >> 10, ws = (r >> 5) & 31, ds = r & 31;
  int h = (hs+2)&31, w = (ws+2)&31, d = (ds+2)&31;
  int src = ((b*32 + h)*32 + w)*32 + d;
  int win = ((b*8 + (hs>>2))*8 + (ws>>2))*8 + (ds>>2);
  int n   = ((hs&3)*4 + (ws&3))*4 + (ds&3);
  int dst = win*64 + n;
  float v[3];
  #pragma unroll
  for (int t=0;t<3;t++) v[t] = x[(size_t)src*192 + lane + t*64];
  float s  = v[0]+v[1]+v[2];
  float s2 = v[0]*v[0]+v[1]*v[1]+v[2]*v[2];
  #pragma unroll
  for (int o=32;o>=1;o>>=1){ s += __shfl_xor(s,o); s2 += __shfl_xor(s2,o); }
  float mean = s*(1.0f/192.0f);
  float var  = s2*(1.0f/192.0f) - mean*mean;
  float rstd = rsqrtf(var + 1e-5f);
  #pragma unroll
  for (int t=0;t<3;t++){
    int c = lane + t*64;
    out[(size_t)dst*192 + c] = f2b((v[t]-mean)*rstd*g[c] + bvec[c]);
  }
}

// ---------------- MFMA GEMM, full-K-chunk, XCD-swizzled grid (unchanged) ----------------
template<int MODE, int NB>
__global__ __launch_bounds__(256) void gemm_fk(
    const u16* __restrict__ A, const u16* __restrict__ BT, const float* __restrict__ bias,
    const int K, const int N,
    u16* __restrict__ outb, float* __restrict__ outf, const float* __restrict__ resf)
{
  __shared__ u16 As[64*192];
  __shared__ u16 Bs[64*192];
  const int lin = blockIdx.x;
  const int xcd = lin & 7, idx = lin >> 3;
  const int mb = idx / NB, nb = idx - mb*NB;
  const int m0 = (xcd*128 + mb) * 64, n0 = nb * 64;
  const int tid = threadIdx.x;
  const int wv = tid >> 6, lane = tid & 63;
  const int quad = lane >> 4, l16 = lane & 15;
  const int wm = (wv >> 1) * 32, wn = (wv & 1) * 32;

  float4v acc[2][2];
  #pragma unroll
  for (int a=0;a<2;a++) for (int b=0;b<2;b++) acc[a][b] = (float4v){0.f,0.f,0.f,0.f};

  const int srow8 = lane >> 3;
  const int scc   = (lane & 7) ^ srow8;
  const int c3x   = l16 & 7;

  for (int kc = 0; kc < K; kc += 192){
    #pragma unroll
    for (int t=0;t<6;t++){
      int ig = wv*6 + t;
      int g = ig >> 3, ro = ig & 7;
      int row = ro*8 + srow8;
      gload_lds16(A  + (size_t)(m0+row)*K + kc + g*64 + scc*8, As + g*4096 + ro*512);
      gload_lds16(BT + (size_t)(n0+row)*K + kc + g*64 + scc*8, Bs + g*4096 + ro*512);
    }
    __syncthreads();
    #pragma unroll
    for (int ks=0; ks<6; ks++){
      const int cc = ks*4 + quad, g = cc >> 3, c3 = (cc & 7) ^ c3x;
      short8 af[2], bf2[2];
      #pragma unroll
      for (int mt=0;mt<2;mt++) af[mt]  = *(const short8*)(As + g*4096 + (wm+mt*16+l16)*64 + c3*8);
      #pragma unroll
      for (int nt=0;nt<2;nt++) bf2[nt] = *(const short8*)(Bs + g*4096 + (wn+nt*16+l16)*64 + c3*8);
      #pragma unroll
      for (int mt=0;mt<2;mt++)
        #pragma unroll
        for (int nt=0;nt<2;nt++)
          acc[mt][nt] = __builtin_amdgcn_mfma_f32_16x16x32_bf16(af[mt], bf2[nt], acc[mt][nt], 0,0,0);
    }
    if (kc + 192 < K) __syncthreads();
  }

  #pragma unroll
  for (int nt=0;nt<2;nt++){
    int col = n0 + wn + nt*16 + l16;
    float bv = bias[col];
    #pragma unroll
    for (int mt=0;mt<2;mt++){
      float4v a = acc[mt][nt];
      #pragma unroll
      for (int r=0;r<4;r++){
        int mrow = m0 + wm + mt*16 + quad*4 + r;
        float v = a[r] + bv;
        if (MODE == 4){
          if (col < 192) v *= 0.17677669529663687f;
          outb[(size_t)mrow*N + col] = f2b(v);
        } else {
          int win = mrow >> 6, n = mrow & 63;
          int b = win >> 9, rw = win & 511;
          int hs = ((rw>>6)&7)*4 + (n>>4);
          int ws = ((rw>>3)&7)*4 + ((n>>2)&3);
          int ds = (rw&7)*4 + (n&3);
          int h=(hs+2)&31, w=(ws+2)&31, d=(ds+2)&31;
          size_t t = (size_t)((b*32+h)*32+w)*32 + d;
          outf[t*192 + col] = v + resf[t*192 + col];
        }
      }
    }
  }
}

// ---------------- fused LN2 + MLP, packed weights, 4 hidden passes of 192 ----------------
// Block = 64 tokens, 512 threads. LDS: Ash 24 KB (ln tile) + Hsh 24 KB (h quarter) = 48 KB;
// epilogue reuses the whole 48 KB as fp32 out-stage so global writes/res-reads are coalesced.
// All weight loads are wave-uniform-base + lane*16B (packed) -> 16 fully-used lines/instr
// instead of 64 quarter-used (the round-7 TA bottleneck).
__global__ __launch_bounds__(512,4) void mlp_fused(
    const float* __restrict__ xo, const float* __restrict__ g2, const float* __restrict__ b2,
    const u16* __restrict__ w1P, const float* __restrict__ bm1,
    const u16* __restrict__ w2P, const float* __restrict__ bm2,
    float* __restrict__ out)
{
  __shared__ u16 S[2*64*192];          // 48 KB
  u16* Ash = S;
  u16* Hsh = S + 64*192;
  const int tid = threadIdx.x;
  const int wv = tid >> 6, lane = tid & 63;
  const int quad = lane >> 4, l16 = lane & 15;
  const int tok0 = blockIdx.x * 64;
  const int c3x = l16 & 7;

  // ---- LN2 in-block: wave wv handles tokens wv*8..wv*8+7, into swizzled Ash ----
  {
    float gg[3], bb[3];
    #pragma unroll
    for (int t=0;t<3;t++){ gg[t] = g2[lane+t*64]; bb[t] = b2[lane+t*64]; }
    #pragma unroll
    for (int tt=0;tt<8;tt++){
      const int tl = wv*8 + tt;
      const float* row = xo + (size_t)(tok0+tl)*192;
      float v[3];
      #pragma unroll
      for (int t=0;t<3;t++) v[t] = row[lane + t*64];
      float s = v[0]+v[1]+v[2];
      float s2 = v[0]*v[0]+v[1]*v[1]+v[2]*v[2];
      #pragma unroll
      for (int o=32;o>=1;o>>=1){ s += __shfl_xor(s,o); s2 += __shfl_xor(s2,o); }
      float mean = s*(1.0f/192.0f);
      float rstd = rsqrtf(s2*(1.0f/192.0f) - mean*mean + 1e-5f);
      const int slot = ((lane>>3) ^ (tl&7));
      #pragma unroll
      for (int t=0;t<3;t++)
        Ash[t*4096 + tl*64 + slot*8 + (lane&7)] = f2b((v[t]-mean)*rstd*gg[t] + bb[t]);
    }
  }
  __syncthreads();

  const int mb   = (wv&3)*3;     // hc/oc tile base (3 tiles)
  const int ntg0 = (wv>>2)*2;    // token tile base (2 tiles)
  float4v dacc[3][2];
  #pragma unroll
  for (int a=0;a<3;a++) for (int b=0;b<2;b++) dacc[a][b] = (float4v){0.f,0.f,0.f,0.f};

  for (int p=0; p<4; p++){
    if (p) __syncthreads();      // prev DOWN done reading Hsh
    // ---- UP quarter: h[p*192 .. +192) ----
    float4v acc[3][2];
    #pragma unroll
    for (int a=0;a<3;a++) for (int b=0;b<2;b++) acc[a][b] = (float4v){0.f,0.f,0.f,0.f};
    #pragma unroll
    for (int ks=0; ks<6; ks++){
      const int cc = ks*4 + quad, g = cc >> 3, c3 = (cc & 7) ^ c3x;
      short8 bf[2], af[3];
      #pragma unroll
      for (int ntl=0;ntl<2;ntl++)
        bf[ntl] = *(const short8*)(Ash + g*4096 + ((ntg0+ntl)*16+l16)*64 + c3*8);
      #pragma unroll
      for (int mtl=0;mtl<3;mtl++)
        af[mtl] = *(const short8*)(w1P + ((size_t)((p*12 + mb + mtl)*6 + ks)*64 + lane)*8);
      #pragma unroll
      for (int mtl=0;mtl<3;mtl++)
        #pragma unroll
        for (int ntl=0;ntl<2;ntl++)
          acc[mtl][ntl] = __builtin_amdgcn_mfma_f32_16x16x32_bf16(af[mtl], bf[ntl], acc[mtl][ntl], 0,0,0);
    }
    // bias + GELU -> swizzled Hsh (row stride 192 u16)
    #pragma unroll
    for (int mtl=0;mtl<3;mtl++){
      const int hl0 = (mb+mtl)*16 + quad*4;        // local hc 0..191
      const float4v bv = *(const float4v*)(bm1 + p*192 + hl0);
      const int g = hl0 >> 3, sub = hl0 & 7;       // sub in {0,4}
      #pragma unroll
      for (int ntl=0;ntl<2;ntl++){
        const int tok = (ntg0+ntl)*16 + l16;
        union { unsigned long long d; u16 u[4]; } pk;
        #pragma unroll
        for (int r=0;r<4;r++) pk.u[r] = f2b(gelu_t(acc[mtl][ntl][r] + bv[r]));
        *(unsigned long long*)(Hsh + tok*192 + ((g ^ (tok&7))<<3) + sub) = pk.d;
      }
    }
    __syncthreads();
    // ---- DOWN quarter: accumulate ----
    #pragma unroll
    for (int ks=0; ks<6; ks++){
      const int g = ks*4 + quad;                   // 0..23
      short8 bf[2], af[3];
      #pragma unroll
      for (int ntl=0;ntl<2;ntl++){
        const int tok = (ntg0+ntl)*16 + l16;
        bf[ntl] = *(const short8*)(Hsh + tok*192 + ((g ^ (tok&7))<<3));
      }
      #pragma unroll
      for (int mtl=0;mtl<3;mtl++)
        af[mtl] = *(const short8*)(w2P + ((size_t)((mb+mtl)*24 + p*6 + ks)*64 + lane)*8);
      #pragma unroll
      for (int mtl=0;mtl<3;mtl++)
        #pragma unroll
        for (int ntl=0;ntl<2;ntl++)
          dacc[mtl][ntl] = __builtin_amdgcn_mfma_f32_16x16x32_bf16(af[mtl], bf[ntl], dacc[mtl][ntl], 0,0,0);
    }
  }
  __syncthreads();

  // ---- epilogue: dacc+bias -> fp32 stage in S (swizzled float4), then coalesced out ----
  float4v* F = (float4v*)S;                        // 3072 float4 = 48 KB
  #pragma unroll
  for (int mtl=0;mtl<3;mtl++){
    const int oc0 = (mb+mtl)*16 + quad*4;
    const float4v bv = *(const float4v*)(bm2 + oc0);
    #pragma unroll
    for (int ntl=0;ntl<2;ntl++){
      const int tok = (ntg0+ntl)*16 + l16;
      float4v o;
      #pragma unroll
      for (int r=0;r<4;r++) o[r] = dacc[mtl][ntl][r] + bv[r];
      F[tok*48 + ((oc0>>2) ^ (tok&7))] = o;
    }
  }
  __syncthreads();
  const float4v* xo4 = (const float4v*)(xo + (size_t)tok0*192);
  float4v* out4 = (float4v*)(out + (size_t)tok0*192);
  #pragma unroll
  for (int it=0; it<6; it++){
    int f = it*512 + tid;
    int tok = f/48, c = f - tok*48;
    float4v v = F[tok*48 + (c ^ (tok&7))];
    float4v xv = xo4[f];
    #pragma unroll
    for (int r=0;r<4;r++) v[r] += xv[r];
    out4[f] = v;
  }
}

// ---------------- MFMA windowed attention (unchanged) ----------------
__global__ __launch_bounds__(192,3) void attn_mfma(
    const u16* __restrict__ qkv, const float* __restrict__ bias_table,
    u16* __restrict__ out)
{
  __shared__ u16  Psh [3][64*72];
  __shared__ u16  VTsh[3][32*72];
  __shared__ float bsh[3][344];
  const int win  = blockIdx.x >> 1;
  const int wv   = threadIdx.x / 64;
  const int lane = threadIdx.x & 63;
  const int hg   = (blockIdx.x & 1)*3 + wv;
  const int quad = lane >> 4, l16 = lane & 15;

  u16* P  = &Psh[wv][0];
  u16* VT = &VTsh[wv][0];
  float* bs = &bsh[wv][0];
  const u16* base = qkv + (size_t)win*64*576 + hg*32;

  for (int idx = lane; idx < 343; idx += 64) bs[idx] = bias_table[idx*6 + hg];

  {
    const int a = (lane & 15)*4 + (lane >> 4);
    #pragma unroll
    for (int t=0;t<4;t++){
      union { uint4 v; u16 u[8]; } vv;
      vv.v = *(const uint4*)(base + (size_t)lane*576 + 384 + t*8);
      #pragma unroll
      for (int e=0;e<8;e++) VT[(t*8+e)*72 + a] = vv.u[e];
    }
  }

  short8 qf[4], kf[4];
  #pragma unroll
  for (int mt=0;mt<4;mt++) qf[mt] = *(const short8*)(base + (size_t)(mt*16 + l16)*576 + quad*8);
  #pragma unroll
  for (int nt=0;nt<4;nt++) kf[nt] = *(const short8*)(base + (size_t)(nt*16 + l16)*576 + 192 + quad*8);

  float4v s[4][4];
  #pragma unroll
  for (int mt=0;mt<4;mt++)
    #pragma unroll
    for (int nt=0;nt<4;nt++)
      s[mt][nt] = __builtin_amdgcn_mfma_f32_16x16x32_bf16(qf[mt], kf[nt], (float4v){0.f,0.f,0.f,0.f}, 0,0,0);

  const int rwn = win & 511;
  const int bh=(rwn>>6)&7, bw=(rwn>>3)&7, bd=rwn&7;
  const int jw = l16>>2, jd = l16&3;
  const int gw_j = (bw==7) ? ((jw  <2)?3:6) : 0;
  const int gd_j = (bd==7) ? ((jd  <2)?1:2) : 0;
  const int gw_i = (bw==7) ? ((quad<2)?3:6) : 0;
  const int laneoff = (quad - jw)*7 - jd + 171;
  #pragma unroll
  for (int mt=0;mt<4;mt++){
    const int gh_i = (bh==7) ? ((mt<2)?9:18) : 0;
    #pragma unroll
    for (int nt=0;nt<4;nt++){
      const int gh_j = (bh==7) ? ((nt<2)?9:18) : 0;
      const int bb = (mt-nt)*49 + laneoff;
      #pragma unroll
      for (int r=0;r<4;r++){
        const int gd_i = (bd==7) ? ((r<2)?1:2) : 0;
        float sv = s[mt][nt][r] + bs[bb + r];
        if ((gh_i + gw_i + gd_i) != (gh_j + gw_j + gd_j)) sv -= 100.f;
        s[mt][nt][r] = sv;
      }
    }
  }

  #pragma unroll
  for (int mt=0;mt<4;mt++){
    #pragma unroll
    for (int r=0;r<4;r++){
      float m0 = fmaxf(fmaxf(s[mt][0][r], s[mt][1][r]), fmaxf(s[mt][2][r], s[mt][3][r]));
      #pragma unroll
      for (int o=8;o>=1;o>>=1) m0 = fmaxf(m0, __shfl_xor(m0,o));
      float sum = 0.f;
      float e[4];
      #pragma unroll
      for (int nt=0;nt<4;nt++){ e[nt] = __expf(s[mt][nt][r] - m0); sum += e[nt]; }
      #pragma unroll
      for (int o=8;o>=1;o>>=1) sum += __shfl_xor(sum,o);
      const float rinv = 1.f/sum;
      union { unsigned long long d; u16 u[4]; } pk;
      #pragma unroll
      for (int nt=0;nt<4;nt++) pk.u[nt] = f2b(e[nt]*rinv);
      *(unsigned long long*)(&P[(mt*16 + quad*4 + r)*72 + l16*4]) = pk.d;
    }
  }

  float4v o2[4][2];
  #pragma unroll
  for (int mt=0;mt<4;mt++){ o2[mt][0]=(float4v){0.f,0.f,0.f,0.f}; o2[mt][1]=(float4v){0.f,0.f,0.f,0.f}; }
  #pragma unroll
  for (int s2=0;s2<2;s2++){
    short8 vfrag[2];
    #pragma unroll
    for (int ct=0;ct<2;ct++) vfrag[ct] = *(const short8*)(&VT[(ct*16 + l16)*72 + s2*32 + quad*8]);
    #pragma unroll
    for (int mt=0;mt<4;mt++){
      short8 pfrag = *(const short8*)(&P[(mt*16 + l16)*72 + s2*32 + quad*8]);
      #pragma unroll
      for (int ct=0;ct<2;ct++)
        o2[mt][ct] = __builtin_amdgcn_mfma_f32_16x16x32_bf16(pfrag, vfrag[ct], o2[mt][ct], 0,0,0);
    }
  }

  #pragma unroll
  for (int mt=0;mt<4;mt++)
    #pragma unroll
    for (int ct=0;ct<2;ct++)
      #pragma unroll
      for (int r=0;r<4;r++){
        int i = mt*16 + quad*4 + r;
        out[((size_t)win*64 + i)*192 + hg*32 + ct*16 + l16] = f2b(o2[mt][ct][r]);
      }
}

// ---------------- driver ----------------
extern "C" void kernel_launch(void* const* d_in, const int* in_sizes, int n_in,
                              void* d_out, int out_size, void* d_ws, size_t ws_size,
                              hipStream_t stream)
{
  const float* x    = (const float*)d_in[0];
  const float* g1   = (const float*)d_in[1];
  const float* b1   = (const float*)d_in[2];
  const float* wqkv = (const float*)d_in[3];
  const float* bqkv = (const float*)d_in[4];
  const float* wo   = (const float*)d_in[5];
  const float* bo   = (const float*)d_in[6];
  const float* btab = (const float*)d_in[7];
  const float* g2   = (const float*)d_in[8];
  const float* b2v  = (const float*)d_in[9];
  const float* w1   = (const float*)d_in[10];
  const float* bm1  = (const float*)d_in[11];
  const float* w2   = (const float*)d_in[12];
  const float* bm2  = (const float*)d_in[13];
  float* out = (float*)d_out;

  char* ws = (char*)d_ws;
  u16*  wqkvT = (u16*)(ws + 0);            // [576][192]
  u16*  woT   = (u16*)(ws + 221184);       // [192][192]
  u16*  w1P   = (u16*)(ws + 294912);       // packed 48x6x512
  u16*  w2P   = (u16*)(ws + 589824);       // packed 12x24x512
  u16*  xw    = (u16*)(ws + 1048576);      // 65536x192 bf16
  u16*  qkvb  = (u16*)(ws + 26214400);     // 65536x576 bf16 (dead after attn)
  float* xo   = (float*)(ws + 26214400);   // 65536x192 fp32 (overlays dead qkv)

  transpose_all<<<1728,256,0,stream>>>(wqkv, wo, w1, w2, wqkvT, woT, w1P, w2P);

  // LN1 + shift + window partition  (fp32 x -> bf16 xw)
  ln_kernel<<<16384,256,0,stream>>>(x, g1, b1, xw);
  // QKV projection (+ q-scale): [65536,192] @ [192,576], XCD-swizzled
  gemm_fk<4,9><<<9216,256,0,stream>>>(xw, wqkvT, bqkv, 192, 576, qkvb, nullptr, nullptr);
  // MFMA windowed attention (writes attn_out over xw)
  attn_mfma<<<2048,192,0,stream>>>(qkvb, btab, xw);
  // output projection + window-reverse + unshift + fp32 x residual -> xo (fp32)
  gemm_fk<2,3><<<3072,256,0,stream>>>(xw, woT, bo, 192, 192, nullptr, xo, x);
  // fused LN2 + MLP (packed weights): out = xo + gelu(ln(xo)@w1+bm1)@w2 + bm2
  mlp_fused<<<1024,512,0,stream>>>(xo, g2, b2v, w1P, bm1, w2P, bm2, out);
}

// Round 9
// 301.153 us; speedup vs baseline: 1.7193x; 1.0480x over previous
//
#include <hip/hip_runtime.h>
#include <math.h>

typedef unsigned short u16;
typedef unsigned int   u32;
using short8  = __attribute__((ext_vector_type(8))) short;
using float4v = __attribute__((ext_vector_type(4))) float;

__device__ __forceinline__ float b2f(u16 u){ return __uint_as_float(((u32)u)<<16); }
__device__ __forceinline__ u16 f2b(float f){
  u32 x = __float_as_uint(f);
  x += 0x7FFFu + ((x>>16)&1u);   // RNE; inputs are tame (no NaN)
  return (u16)(x>>16);
}

// async global->LDS, 16B per lane. LDS dest = wave-uniform base + lane*16.
__device__ __forceinline__ void gload_lds16(const u16* g, u16* l){
  __builtin_amdgcn_global_load_lds((const __attribute__((address_space(1))) void*)g,
                                   (__attribute__((address_space(3))) void*)l, 16, 0, 0);
}

// tanh-form GELU: |err vs exact erf-GELU| <~3e-3
__device__ __forceinline__ float gelu_t(float x){
  float u = 1.5957691216f*(x + 0.044715f*x*x*x);
  float t = 1.f - 2.f/(1.f + __expf(u));
  return 0.5f*x*(1.f + t);
}

// ------- weight prep: wqkvT/woT transposed; w1P/w2P packed in MFMA A-fragment order -------
__global__ void transpose_all(const float* __restrict__ wqkv, const float* __restrict__ wo,
                              const float* __restrict__ w1,   const float* __restrict__ w2,
                              u16* __restrict__ wqkvT, u16* __restrict__ woT,
                              u16* __restrict__ w1P,   u16* __restrict__ w2P){
  int idx = blockIdx.x*256 + threadIdx.x;
  if (idx < 110592){ int r=idx/576, c=idx-r*576; wqkvT[c*192+r]=f2b(wqkv[idx]); }
  else if (idx < 147456){ int j=idx-110592; int r=j/192, c=j-r*192; woT[c*192+r]=f2b(wo[j]); }
  else if (idx < 294912){
    int j = idx-147456;
    int tile = j >> 9, w = j & 511;            // tile = hct*6+ks
    int e = w & 7, l16 = (w>>3)&15, quad = w>>7;
    int hc = (tile/6)*16 + l16, k = (tile%6)*32 + quad*8 + e;
    w1P[j] = f2b(w1[k*768 + hc]);
  } else if (idx < 442368){
    int j = idx-294912;
    int tile = j >> 9, w = j & 511;            // tile = oct*24+kk
    int e = w & 7, l16 = (w>>3)&15, quad = w>>7;
    int oc = (tile/24)*16 + l16, k = (tile%24)*32 + quad*8 + e;
    w2P[j] = f2b(w2[k*192 + oc]);
  }
}

// ---------------- LayerNorm1 (fp32 in, bf16 out) + roll(-2) + window partition ----------------
__global__ __launch_bounds__(256) void ln_kernel(const float* __restrict__ x,
    const float* __restrict__ g, const float* __restrict__ bvec,
    u16* __restrict__ out)
{
  int wave = threadIdx.x >> 6, lane = threadIdx.x & 63;
  int token = blockIdx.x*4 + wave;          // enumerates SHIFTED coords
  int b = token >> 15, r = token & 32767;
  int hs = r >> 10, ws = (r >> 5) & 31, ds = r & 31;
  int h = (hs+2)&31, w = (ws+2)&31, d = (ds+2)&31;
  int src = ((b*32 + h)*32 + w)*32 + d;
  int win = ((b*8 + (hs>>2))*8 + (ws>>2))*8 + (ds>>2);
  int n   = ((hs&3)*4 + (ws&3))*4 + (ds&3);
  int dst = win*64 + n;
  float v[3];
  #pragma unroll
  for (int t=0;t<3;t++) v[t] = x[(size_t)src*192 + lane + t*64];
  float s  = v[0]+v[1]+v[2];
  float s2 = v[0]*v[0]+v[1]*v[1]+v[2]*v[2];
  #pragma unroll
  for (int o=32;o>=1;o>>=1){ s += __shfl_xor(s,o); s2 += __shfl_xor(s2,o); }
  float mean = s*(1.0f/192.0f);
  float var  = s2*(1.0f/192.0f) - mean*mean;
  float rstd = rsqrtf(var + 1e-5f);
  #pragma unroll
  for (int t=0;t<3;t++){
    int c = lane + t*64;
    out[(size_t)dst*192 + c] = f2b((v[t]-mean)*rstd*g[c] + bvec[c]);
  }
}

// ---------------- MFMA GEMM, full-K-chunk, XCD-swizzled grid (unchanged) ----------------
template<int MODE, int NB>
__global__ __launch_bounds__(256) void gemm_fk(
    const u16* __restrict__ A, const u16* __restrict__ BT, const float* __restrict__ bias,
    const int K, const int N,
    u16* __restrict__ outb, float* __restrict__ outf, const float* __restrict__ resf)
{
  __shared__ u16 As[64*192];
  __shared__ u16 Bs[64*192];
  const int lin = blockIdx.x;
  const int xcd = lin & 7, idx = lin >> 3;
  const int mb = idx / NB, nb = idx - mb*NB;
  const int m0 = (xcd*128 + mb) * 64, n0 = nb * 64;
  const int tid = threadIdx.x;
  const int wv = tid >> 6, lane = tid & 63;
  const int quad = lane >> 4, l16 = lane & 15;
  const int wm = (wv >> 1) * 32, wn = (wv & 1) * 32;

  float4v acc[2][2];
  #pragma unroll
  for (int a=0;a<2;a++) for (int b=0;b<2;b++) acc[a][b] = (float4v){0.f,0.f,0.f,0.f};

  const int srow8 = lane >> 3;
  const int scc   = (lane & 7) ^ srow8;
  const int c3x   = l16 & 7;

  for (int kc = 0; kc < K; kc += 192){
    #pragma unroll
    for (int t=0;t<6;t++){
      int ig = wv*6 + t;
      int g = ig >> 3, ro = ig & 7;
      int row = ro*8 + srow8;
      gload_lds16(A  + (size_t)(m0+row)*K + kc + g*64 + scc*8, As + g*4096 + ro*512);
      gload_lds16(BT + (size_t)(n0+row)*K + kc + g*64 + scc*8, Bs + g*4096 + ro*512);
    }
    __syncthreads();
    #pragma unroll
    for (int ks=0; ks<6; ks++){
      const int cc = ks*4 + quad, g = cc >> 3, c3 = (cc & 7) ^ c3x;
      short8 af[2], bf2[2];
      #pragma unroll
      for (int mt=0;mt<2;mt++) af[mt]  = *(const short8*)(As + g*4096 + (wm+mt*16+l16)*64 + c3*8);
      #pragma unroll
      for (int nt=0;nt<2;nt++) bf2[nt] = *(const short8*)(Bs + g*4096 + (wn+nt*16+l16)*64 + c3*8);
      #pragma unroll
      for (int mt=0;mt<2;mt++)
        #pragma unroll
        for (int nt=0;nt<2;nt++)
          acc[mt][nt] = __builtin_amdgcn_mfma_f32_16x16x32_bf16(af[mt], bf2[nt], acc[mt][nt], 0,0,0);
    }
    if (kc + 192 < K) __syncthreads();
  }

  #pragma unroll
  for (int nt=0;nt<2;nt++){
    int col = n0 + wn + nt*16 + l16;
    float bv = bias[col];
    #pragma unroll
    for (int mt=0;mt<2;mt++){
      float4v a = acc[mt][nt];
      #pragma unroll
      for (int r=0;r<4;r++){
        int mrow = m0 + wm + mt*16 + quad*4 + r;
        float v = a[r] + bv;
        if (MODE == 4){
          if (col < 192) v *= 0.17677669529663687f;
          outb[(size_t)mrow*N + col] = f2b(v);
        } else {
          int win = mrow >> 6, n = mrow & 63;
          int b = win >> 9, rw = win & 511;
          int hs = ((rw>>6)&7)*4 + (n>>4);
          int ws = ((rw>>3)&7)*4 + ((n>>2)&3);
          int ds = (rw&7)*4 + (n&3);
          int h=(hs+2)&31, w=(ws+2)&31, d=(ds+2)&31;
          size_t t = (size_t)((b*32+h)*32+w)*32 + d;
          outf[t*192 + col] = v + resf[t*192 + col];
        }
      }
    }
  }
}

// ---------------- fused LN2 + MLP: 32 tokens/block, 256 threads, 24 KB LDS ----------------
// Round-9 re-block: same per-wave code as round 8 (3 hc/oc tiles x 2 token-tiles per wave,
// packed weight fragments, swizzled Ash/Hsh), but half the tokens per block ->
// 24 KB LDS -> 6 resident blocks/CU (vs 3) and grid 2048 (8 blocks/CU of work) so the
// barrier chain is covered by concurrency instead of stalling (round-8 latency wall).
__global__ __launch_bounds__(256) void mlp_fused(
    const float* __restrict__ xo, const float* __restrict__ g2, const float* __restrict__ b2,
    const u16* __restrict__ w1P, const float* __restrict__ bm1,
    const u16* __restrict__ w2P, const float* __restrict__ bm2,
    float* __restrict__ out)
{
  __shared__ u16 S[2*32*192];          // 24 KB
  u16* Ash = S;                        // 32 tok x 192 (3 k-groups of 64)
  u16* Hsh = S + 32*192;               // 32 tok x 192 hidden quarter
  const int tid = threadIdx.x;
  const int wv = tid >> 6, lane = tid & 63;
  const int quad = lane >> 4, l16 = lane & 15;
  const int tok0 = blockIdx.x * 32;
  const int c3x = l16 & 7;

  // ---- LN2 in-block: wave wv handles tokens wv*8..wv*8+7, into swizzled Ash ----
  {
    float gg[3], bb[3];
    #pragma unroll
    for (int t=0;t<3;t++){ gg[t] = g2[lane+t*64]; bb[t] = b2[lane+t*64]; }
    #pragma unroll
    for (int tt=0;tt<8;tt++){
      const int tl = wv*8 + tt;
      const float* row = xo + (size_t)(tok0+tl)*192;
      float v[3];
      #pragma unroll
      for (int t=0;t<3;t++) v[t] = row[lane + t*64];
      float s = v[0]+v[1]+v[2];
      float s2 = v[0]*v[0]+v[1]*v[1]+v[2]*v[2];
      #pragma unroll
      for (int o=32;o>=1;o>>=1){ s += __shfl_xor(s,o); s2 += __shfl_xor(s2,o); }
      float mean = s*(1.0f/192.0f);
      float rstd = rsqrtf(s2*(1.0f/192.0f) - mean*mean + 1e-5f);
      const int slot = ((lane>>3) ^ (tl&7));
      #pragma unroll
      for (int t=0;t<3;t++)
        Ash[t*2048 + tl*64 + slot*8 + (lane&7)] = f2b((v[t]-mean)*rstd*gg[t] + bb[t]);
    }
  }
  __syncthreads();

  const int mb = wv*3;           // hc/oc tile base (3 tiles per wave, 12 total)
  float4v dacc[3][2];
  #pragma unroll
  for (int a=0;a<3;a++) for (int b=0;b<2;b++) dacc[a][b] = (float4v){0.f,0.f,0.f,0.f};

  for (int p=0; p<4; p++){
    if (p) __syncthreads();      // prev DOWN done reading Hsh
    // ---- UP quarter: h[p*192 .. +192) ----
    float4v acc[3][2];
    #pragma unroll
    for (int a=0;a<3;a++) for (int b=0;b<2;b++) acc[a][b] = (float4v){0.f,0.f,0.f,0.f};
    #pragma unroll
    for (int ks=0; ks<6; ks++){
      const int cc = ks*4 + quad, g = cc >> 3, c3 = (cc & 7) ^ c3x;
      short8 bf[2], af[3];
      #pragma unroll
      for (int ntl=0;ntl<2;ntl++)
        bf[ntl] = *(const short8*)(Ash + g*2048 + (ntl*16+l16)*64 + c3*8);
      #pragma unroll
      for (int mtl=0;mtl<3;mtl++)
        af[mtl] = *(const short8*)(w1P + ((size_t)((p*12 + mb + mtl)*6 + ks)*64 + lane)*8);
      #pragma unroll
      for (int mtl=0;mtl<3;mtl++)
        #pragma unroll
        for (int ntl=0;ntl<2;ntl++)
          acc[mtl][ntl] = __builtin_amdgcn_mfma_f32_16x16x32_bf16(af[mtl], bf[ntl], acc[mtl][ntl], 0,0,0);
    }
    // bias + GELU -> swizzled Hsh (row stride 192 u16)
    #pragma unroll
    for (int mtl=0;mtl<3;mtl++){
      const int hl0 = (mb+mtl)*16 + quad*4;        // local hc 0..191
      const float4v bv = *(const float4v*)(bm1 + p*192 + hl0);
      const int g = hl0 >> 3, sub = hl0 & 7;       // sub in {0,4}
      #pragma unroll
      for (int ntl=0;ntl<2;ntl++){
        const int tok = ntl*16 + l16;
        union { unsigned long long d; u16 u[4]; } pk;
        #pragma unroll
        for (int r=0;r<4;r++) pk.u[r] = f2b(gelu_t(acc[mtl][ntl][r] + bv[r]));
        *(unsigned long long*)(Hsh + tok*192 + ((g ^ (tok&7))<<3) + sub) = pk.d;
      }
    }
    __syncthreads();
    // ---- DOWN quarter: accumulate ----
    #pragma unroll
    for (int ks=0; ks<6; ks++){
      const int g = ks*4 + quad;                   // 0..23
      short8 bf[2], af[3];
      #pragma unroll
      for (int ntl=0;ntl<2;ntl++){
        const int tok = ntl*16 + l16;
        bf[ntl] = *(const short8*)(Hsh + tok*192 + ((g ^ (tok&7))<<3));
      }
      #pragma unroll
      for (int mtl=0;mtl<3;mtl++)
        af[mtl] = *(const short8*)(w2P + ((size_t)((mb+mtl)*24 + p*6 + ks)*64 + lane)*8);
      #pragma unroll
      for (int mtl=0;mtl<3;mtl++)
        #pragma unroll
        for (int ntl=0;ntl<2;ntl++)
          dacc[mtl][ntl] = __builtin_amdgcn_mfma_f32_16x16x32_bf16(af[mtl], bf[ntl], dacc[mtl][ntl], 0,0,0);
    }
  }
  __syncthreads();

  // ---- epilogue: dacc+bias -> fp32 stage in S (swizzled float4), then coalesced out ----
  float4v* F = (float4v*)S;                        // 1536 float4 = 24 KB
  #pragma unroll
  for (int mtl=0;mtl<3;mtl++){
    const int oc0 = (mb+mtl)*16 + quad*4;
    const float4v bv = *(const float4v*)(bm2 + oc0);
    #pragma unroll
    for (int ntl=0;ntl<2;ntl++){
      const int tok = ntl*16 + l16;
      float4v o;
      #pragma unroll
      for (int r=0;r<4;r++) o[r] = dacc[mtl][ntl][r] + bv[r];
      F[tok*48 + ((oc0>>2) ^ (tok&7))] = o;
    }
  }
  __syncthreads();
  const float4v* xo4 = (const float4v*)(xo + (size_t)tok0*192);
  float4v* out4 = (float4v*)(out + (size_t)tok0*192);
  #pragma unroll
  for (int it=0; it<6; it++){
    int f = it*256 + tid;
    int tok = f/48, c = f - tok*48;
    float4v v = F[tok*48 + (c ^ (tok&7))];
    float4v xv = xo4[f];
    #pragma unroll
    for (int r=0;r<4;r++) v[r] += xv[r];
    out4[f] = v;
  }
}

// ---------------- MFMA windowed attention (unchanged) ----------------
__global__ __launch_bounds__(192,3) void attn_mfma(
    const u16* __restrict__ qkv, const float* __restrict__ bias_table,
    u16* __restrict__ out)
{
  __shared__ u16  Psh [3][64*72];
  __shared__ u16  VTsh[3][32*72];
  __shared__ float bsh[3][344];
  const int win  = blockIdx.x >> 1;
  const int wv   = threadIdx.x / 64;
  const int lane = threadIdx.x & 63;
  const int hg   = (blockIdx.x & 1)*3 + wv;
  const int quad = lane >> 4, l16 = lane & 15;

  u16* P  = &Psh[wv][0];
  u16* VT = &VTsh[wv][0];
  float* bs = &bsh[wv][0];
  const u16* base = qkv + (size_t)win*64*576 + hg*32;

  for (int idx = lane; idx < 343; idx += 64) bs[idx] = bias_table[idx*6 + hg];

  {
    const int a = (lane & 15)*4 + (lane >> 4);
    #pragma unroll
    for (int t=0;t<4;t++){
      union { uint4 v; u16 u[8]; } vv;
      vv.v = *(const uint4*)(base + (size_t)lane*576 + 384 + t*8);
      #pragma unroll
      for (int e=0;e<8;e++) VT[(t*8+e)*72 + a] = vv.u[e];
    }
  }

  short8 qf[4], kf[4];
  #pragma unroll
  for (int mt=0;mt<4;mt++) qf[mt] = *(const short8*)(base + (size_t)(mt*16 + l16)*576 + quad*8);
  #pragma unroll
  for (int nt=0;nt<4;nt++) kf[nt] = *(const short8*)(base + (size_t)(nt*16 + l16)*576 + 192 + quad*8);

  float4v s[4][4];
  #pragma unroll
  for (int mt=0;mt<4;mt++)
    #pragma unroll
    for (int nt=0;nt<4;nt++)
      s[mt][nt] = __builtin_amdgcn_mfma_f32_16x16x32_bf16(qf[mt], kf[nt], (float4v){0.f,0.f,0.f,0.f}, 0,0,0);

  const int rwn = win & 511;
  const int bh=(rwn>>6)&7, bw=(rwn>>3)&7, bd=rwn&7;
  const int jw = l16>>2, jd = l16&3;
  const int gw_j = (bw==7) ? ((jw  <2)?3:6) : 0;
  const int gd_j = (bd==7) ? ((jd  <2)?1:2) : 0;
  const int gw_i = (bw==7) ? ((quad<2)?3:6) : 0;
  const int laneoff = (quad - jw)*7 - jd + 171;
  #pragma unroll
  for (int mt=0;mt<4;mt++){
    const int gh_i = (bh==7) ? ((mt<2)?9:18) : 0;
    #pragma unroll
    for (int nt=0;nt<4;nt++){
      const int gh_j = (bh==7) ? ((nt<2)?9:18) : 0;
      const int bb = (mt-nt)*49 + laneoff;
      #pragma unroll
      for (int r=0;r<4;r++){
        const int gd_i = (bd==7) ? ((r<2)?1:2) : 0;
        float sv = s[mt][nt][r] + bs[bb + r];
        if ((gh_i + gw_i + gd_i) != (gh_j + gw_j + gd_j)) sv -= 100.f;
        s[mt][nt][r] = sv;
      }
    }
  }

  #pragma unroll
  for (int mt=0;mt<4;mt++){
    #pragma unroll
    for (int r=0;r<4;r++){
      float m0 = fmaxf(fmaxf(s[mt][0][r], s[mt][1][r]), fmaxf(s[mt][2][r], s[mt][3][r]));
      #pragma unroll
      for (int o=8;o>=1;o>>=1) m0 = fmaxf(m0, __shfl_xor(m0,o));
      float sum = 0.f;
      float e[4];
      #pragma unroll
      for (int nt=0;nt<4;nt++){ e[nt] = __expf(s[mt][nt][r] - m0); sum += e[nt]; }
      #pragma unroll
      for (int o=8;o>=1;o>>=1) sum += __shfl_xor(sum,o);
      const float rinv = 1.f/sum;
      union { unsigned long long d; u16 u[4]; } pk;
      #pragma unroll
      for (int nt=0;nt<4;nt++) pk.u[nt] = f2b(e[nt]*rinv);
      *(unsigned long long*)(&P[(mt*16 + quad*4 + r)*72 + l16*4]) = pk.d;
    }
  }

  float4v o2[4][2];
  #pragma unroll
  for (int mt=0;mt<4;mt++){ o2[mt][0]=(float4v){0.f,0.f,0.f,0.f}; o2[mt][1]=(float4v){0.f,0.f,0.f,0.f}; }
  #pragma unroll
  for (int s2=0;s2<2;s2++){
    short8 vfrag[2];
    #pragma unroll
    for (int ct=0;ct<2;ct++) vfrag[ct] = *(const short8*)(&VT[(ct*16 + l16)*72 + s2*32 + quad*8]);
    #pragma unroll
    for (int mt=0;mt<4;mt++){
      short8 pfrag = *(const short8*)(&P[(mt*16 + l16)*72 + s2*32 + quad*8]);
      #pragma unroll
      for (int ct=0;ct<2;ct++)
        o2[mt][ct] = __builtin_amdgcn_mfma_f32_16x16x32_bf16(pfrag, vfrag[ct], o2[mt][ct], 0,0,0);
    }
  }

  #pragma unroll
  for (int mt=0;mt<4;mt++)
    #pragma unroll
    for (int ct=0;ct<2;ct++)
      #pragma unroll
      for (int r=0;r<4;r++){
        int i = mt*16 + quad*4 + r;
        out[((size_t)win*64 + i)*192 + hg*32 + ct*16 + l16] = f2b(o2[mt][ct][r]);
      }
}

// ---------------- driver ----------------
extern "C" void kernel_launch(void* const* d_in, const int* in_sizes, int n_in,
                              void* d_out, int out_size, void* d_ws, size_t ws_size,
                              hipStream_t stream)
{
  const float* x    = (const float*)d_in[0];
  const float* g1   = (const float*)d_in[1];
  const float* b1   = (const float*)d_in[2];
  const float* wqkv = (const float*)d_in[3];
  const float* bqkv = (const float*)d_in[4];
  const float* wo   = (const float*)d_in[5];
  const float* bo   = (const float*)d_in[6];
  const float* btab = (const float*)d_in[7];
  const float* g2   = (const float*)d_in[8];
  const float* b2v  = (const float*)d_in[9];
  const float* w1   = (const float*)d_in[10];
  const float* bm1  = (const float*)d_in[11];
  const float* w2   = (const float*)d_in[12];
  const float* bm2  = (const float*)d_in[13];
  float* out = (float*)d_out;

  char* ws = (char*)d_ws;
  u16*  wqkvT = (u16*)(ws + 0);            // [576][192]
  u16*  woT   = (u16*)(ws + 221184);       // [192][192]
  u16*  w1P   = (u16*)(ws + 294912);       // packed 48x6x512
  u16*  w2P   = (u16*)(ws + 589824);       // packed 12x24x512
  u16*  xw    = (u16*)(ws + 1048576);      // 65536x192 bf16
  u16*  qkvb  = (u16*)(ws + 26214400);     // 65536x576 bf16 (dead after attn)
  float* xo   = (float*)(ws + 26214400);   // 65536x192 fp32 (overlays dead qkv)

  transpose_all<<<1728,256,0,stream>>>(wqkv, wo, w1, w2, wqkvT, woT, w1P, w2P);

  // LN1 + shift + window partition  (fp32 x -> bf16 xw)
  ln_kernel<<<16384,256,0,stream>>>(x, g1, b1, xw);
  // QKV projection (+ q-scale): [65536,192] @ [192,576], XCD-swizzled
  gemm_fk<4,9><<<9216,256,0,stream>>>(xw, wqkvT, bqkv, 192, 576, qkvb, nullptr, nullptr);
  // MFMA windowed attention (writes attn_out over xw)
  attn_mfma<<<2048,192,0,stream>>>(qkvb, btab, xw);
  // output projection + window-reverse + unshift + fp32 x residual -> xo (fp32)
  gemm_fk<2,3><<<3072,256,0,stream>>>(xw, woT, bo, 192, 192, nullptr, xo, x);
  // fused LN2 + MLP: out = xo + gelu(ln(xo)@w1+bm1)@w2 + bm2
  mlp_fused<<<2048,256,0,stream>>>(xo, g2, b2v, w1P, bm1, w2P, bm2, out);
}